// Round 4
// baseline (1198.990 us; speedup 1.0000x reference)
//
#include <hip/hip_runtime.h>
#include <hip/hip_bf16.h>
#include <stdint.h>

#define TTOK 2048
#define DDIM 2048
#define IDIM 5632
#define NEXP 8

typedef __attribute__((ext_vector_type(8))) short bf16x8;
typedef __attribute__((ext_vector_type(4))) float f32x4;
typedef __attribute__((ext_vector_type(8))) unsigned short u16x8;
typedef __attribute__((ext_vector_type(4))) unsigned short u16x4;

__device__ __forceinline__ unsigned short f2bf(float f) {
  union { float f; uint32_t u; } v; v.f = f;
  uint32_t u = v.u + 0x7fffu + ((v.u >> 16) & 1u);
  return (unsigned short)(u >> 16);
}

__device__ __forceinline__ u16x8 cvt8(float4 a, float4 b) {
  u16x8 r;
  r[0]=f2bf(a.x); r[1]=f2bf(a.y); r[2]=f2bf(a.z); r[3]=f2bf(a.w);
  r[4]=f2bf(b.x); r[5]=f2bf(b.y); r[6]=f2bf(b.z); r[7]=f2bf(b.w);
  return r;
}

typedef __attribute__((address_space(3))) void lds_t;
typedef const __attribute__((address_space(1))) void gbl_t;
__device__ __forceinline__ void gload16(const void* g, void* l) {
  __builtin_amdgcn_global_load_lds((gbl_t*)g, (lds_t*)l, 16, 0, 0);
}

// counted-vmcnt pipeline barriers: 12 = 4 A-gloads + 8 B reg-loads stay in flight
#define PIPE_BAR1() asm volatile("s_waitcnt vmcnt(12) lgkmcnt(0)\n\ts_barrier" ::: "memory")
#define PIPE_BAR2() asm volatile("s_barrier" ::: "memory")

// ---------------- router: logits, top-2, softmax, expert lists, x->bf16 ----------------
__global__ __launch_bounds__(256) void router_kernel(
    const float* __restrict__ x, const float* __restrict__ gw,
    unsigned short* __restrict__ xbf,
    int* __restrict__ cnt, int* __restrict__ slots, float* __restrict__ wts)
{
  const int lane = threadIdx.x & 63;
  const int t = (blockIdx.x * blockDim.x + threadIdx.x) >> 6;  // one wave per token
  const float* xr = x + (size_t)t * DDIM;
  float acc[NEXP];
#pragma unroll
  for (int e = 0; e < NEXP; ++e) acc[e] = 0.f;
#pragma unroll
  for (int it = 0; it < DDIM / 256; ++it) {
    const int d = (it * 64 + lane) * 4;
    const float4 xv = *(const float4*)(xr + d);
    u16x4 xb; xb[0]=f2bf(xv.x); xb[1]=f2bf(xv.y); xb[2]=f2bf(xv.z); xb[3]=f2bf(xv.w);
    *(u16x4*)(xbf + (size_t)t * DDIM + d) = xb;
#pragma unroll
    for (int e = 0; e < NEXP; ++e) {
      const float4 gv = *(const float4*)(gw + (size_t)e * DDIM + d);
      acc[e] += xv.x*gv.x + xv.y*gv.y + xv.z*gv.z + xv.w*gv.w;
    }
  }
#pragma unroll
  for (int e = 0; e < NEXP; ++e) {
    float v = acc[e];
#pragma unroll
    for (int off = 32; off > 0; off >>= 1) v += __shfl_xor(v, off);
    acc[e] = v;
  }
  if (lane == 0) {
    int i0 = 0; float v0 = acc[0];
#pragma unroll
    for (int e = 1; e < NEXP; ++e) if (acc[e] > v0) { v0 = acc[e]; i0 = e; }
    int i1 = -1; float v1 = -3.4e38f;
#pragma unroll
    for (int e = 0; e < NEXP; ++e) { if (e == i0) continue; if (acc[e] > v1) { v1 = acc[e]; i1 = e; } }
    const float e1 = __expf(v1 - v0);
    const float w0 = 1.f / (1.f + e1);
    const float w1 = e1 / (1.f + e1);
    const int p0 = atomicAdd(&cnt[i0], 1);
    slots[i0 * TTOK + p0] = t * 2;     wts[i0 * TTOK + p0] = w0;
    const int p1 = atomicAdd(&cnt[i1], 1);
    slots[i1 * TTOK + p1] = t * 2 + 1; wts[i1 * TTOK + p1] = w1;
  }
}

// chunk swizzle: 16B chunk c of row r stored at chunk c ^ (r & 7)

// ---------------- gate+up grouped GEMM: 128M x 64N x 2 mats, BK=64, counted-vmcnt pipeline ----------------
__global__ __launch_bounds__(256) void gateup_kernel(
    const unsigned short* __restrict__ xbf,
    const float* __restrict__ wg, const float* __restrict__ wu,
    const int* __restrict__ cnt, const int* __restrict__ slots,
    unsigned short* __restrict__ h)
{
  const int L = (blockIdx.x & 7) * 1408 + (blockIdx.x >> 3);
  const int mt = L & 15;
  const int n0 = ((L >> 4) % 88) * 64;
  const int e  = L / (16 * 88);
  const int count = cnt[e];
  const int m0 = mt * 128;
  if (m0 >= count) return;

  __shared__ unsigned short A[2][128][64];   // dbuf, 32 KB
  __shared__ unsigned short Bg[64][64];      // single buf, 8 KB
  __shared__ unsigned short Bu[64][64];      // single buf, 8 KB
  __shared__ int rslot[128];
  __shared__ int rtok[128];

  const int tid = threadIdx.x;
  const int lane = tid & 63;
  const int wid = tid >> 6;

  if (tid < 128) {
    const int idx = m0 + tid;
    const int safe = slots[e * TTOK + m0];
    const int s = (idx < count) ? slots[e * TTOK + idx] : safe;
    rslot[tid] = (idx < count) ? s : -1;
    rtok[tid] = s >> 1;
  }
  __syncthreads();

  // A gather: per-lane global src, chunk pre-swizzled so linear gload_lds dest = swizzled LDS
  const int aswz = ((lane & 7) ^ ((lane >> 3) & 7)) * 8;
  const unsigned short* aptr[4];
#pragma unroll
  for (int j = 0; j < 4; ++j) {
    const int arow = wid * 32 + j * 8 + (lane >> 3);
    aptr[j] = xbf + (size_t)rtok[arow] * DDIM + aswz;
  }

  // B staging addresses: 16 fp32 per thread per matrix
  const int brow = tid >> 2;
  const int bcb = (tid & 3) * 2;      // base 16B-chunk index (of 8)
  const int bswz = brow & 7;
  const size_t wboff = (size_t)e * IDIM * DDIM + (size_t)(n0 + brow) * DDIM + bcb * 8;
  const float* gsrc = wg + wboff;
  const float* usrc = wu + wboff;

  const int wr = wid >> 1, wc = wid & 1;
  const int fr = lane & 15;
  const int kc = lane >> 4;
  const int rsw = fr & 7;

  f32x4 accg[4][2] = {};
  f32x4 accu[4][2] = {};

  // prologue: issue A(0) [4 vmem], load B(0) regs [8 vmem]
#pragma unroll
  for (int j = 0; j < 4; ++j) gload16(aptr[j], &A[0][wid * 32][0] + j * 512);
  float4 pg4[4], pu4[4];
#pragma unroll
  for (int q = 0; q < 4; ++q) { pg4[q] = *(const float4*)(gsrc + q * 4); pu4[q] = *(const float4*)(usrc + q * 4); }

#pragma unroll 2
  for (int t = 0; t < 32; ++t) {
    const int cur = t & 1;
    const int kp = (t < 31) ? (t + 1) * 64 : 31 * 64;  // clamped prefetch offset

    // step 1: A(t+1) direct-to-LDS into bufA[cur^1]
#pragma unroll
    for (int j = 0; j < 4; ++j) gload16(aptr[j] + kp, &A[cur ^ 1][wid * 32][0] + j * 512);
    // step 2: B(t+1) into regs
    float4 ng4[4], nu4[4];
#pragma unroll
    for (int q = 0; q < 4; ++q) { ng4[q] = *(const float4*)(gsrc + kp + q * 4); nu4[q] = *(const float4*)(usrc + kp + q * 4); }
    __builtin_amdgcn_sched_barrier(0);
    // step 3: cvt + ds_write B(t) (compiler inserts counted vmcnt for pg4/pu4)
#pragma unroll
    for (int qq = 0; qq < 2; ++qq) {
      const int oc = ((bcb + qq) ^ bswz) * 8;
      *(u16x8*)&Bg[brow][oc] = cvt8(pg4[qq * 2], pg4[qq * 2 + 1]);
      *(u16x8*)&Bu[brow][oc] = cvt8(pu4[qq * 2], pu4[qq * 2 + 1]);
    }
    // barrier #1: A(t) done (older than the 12 in flight), B(t) ds_writes visible
    PIPE_BAR1();

    __builtin_amdgcn_s_setprio(1);
#pragma unroll
    for (int kk = 0; kk < 2; ++kk) {
      bf16x8 a[4], bg[2], bu[2];
      const int cs = ((kk * 4 + kc) ^ rsw) * 8;
#pragma unroll
      for (int mf = 0; mf < 4; ++mf)
        a[mf] = *(const bf16x8*)&A[cur][wr * 64 + mf * 16 + fr][cs];
#pragma unroll
      for (int nf = 0; nf < 2; ++nf) {
        bg[nf] = *(const bf16x8*)&Bg[wc * 32 + nf * 16 + fr][cs];
        bu[nf] = *(const bf16x8*)&Bu[wc * 32 + nf * 16 + fr][cs];
      }
#pragma unroll
      for (int mf = 0; mf < 4; ++mf)
#pragma unroll
        for (int nf = 0; nf < 2; ++nf) {
          accg[mf][nf] = __builtin_amdgcn_mfma_f32_16x16x32_bf16(a[mf], bg[nf], accg[mf][nf], 0, 0, 0);
          accu[mf][nf] = __builtin_amdgcn_mfma_f32_16x16x32_bf16(a[mf], bu[nf], accu[mf][nf], 0, 0, 0);
        }
    }
    __builtin_amdgcn_s_setprio(0);

    // barrier #2: all waves done reading this tile's LDS before next body's writes
    PIPE_BAR2();

    // rotate B regs
#pragma unroll
    for (int q = 0; q < 4; ++q) { pg4[q] = ng4[q]; pu4[q] = nu4[q]; }
  }

#pragma unroll
  for (int mf = 0; mf < 4; ++mf)
#pragma unroll
    for (int nf = 0; nf < 2; ++nf)
#pragma unroll
      for (int j = 0; j < 4; ++j) {
        const int r = wr * 64 + mf * 16 + (lane >> 4) * 4 + j;
        const int s = rslot[r];
        if (s >= 0) {
          const float g = accg[mf][nf][j];
          const float u = accu[mf][nf][j];
          const float hv = g / (1.f + __expf(-g)) * u;
          h[(size_t)s * IDIM + n0 + wc * 32 + nf * 16 + fr] = f2bf(hv);
        }
      }
}

// ---------------- down grouped GEMM: 128M x 128N, BK=64, counted-vmcnt pipeline, scatter-add ----------------
__global__ __launch_bounds__(256) void down_kernel(
    const unsigned short* __restrict__ h,
    const float* __restrict__ wd,
    const int* __restrict__ cnt, const int* __restrict__ slots,
    const float* __restrict__ wts,
    float* __restrict__ out)
{
  const int L = (blockIdx.x & 7) * 256 + (blockIdx.x >> 3);
  const int mt = L & 15;
  const int n0 = ((L >> 4) & 15) * 128;
  const int e  = L >> 8;
  const int count = cnt[e];
  const int m0 = mt * 128;
  if (m0 >= count) return;

  __shared__ unsigned short A[2][128][64];   // dbuf, 32 KB
  __shared__ unsigned short B[128][64];      // single buf, 16 KB
  __shared__ int rslot[128];
  __shared__ float rw[128];

  const int tid = threadIdx.x;
  const int lane = tid & 63;
  const int wid = tid >> 6;

  if (tid < 128) {
    const int idx = m0 + tid;
    const int safe = slots[e * TTOK + m0];
    const int s = (idx < count) ? slots[e * TTOK + idx] : safe;
    rslot[tid] = (idx < count) ? s : (safe | 0x40000000);
    rw[tid] = (idx < count) ? wts[e * TTOK + idx] : 0.f;
  }
  __syncthreads();

  const int aswz = ((lane & 7) ^ ((lane >> 3) & 7)) * 8;
  const unsigned short* aptr[4];
#pragma unroll
  for (int j = 0; j < 4; ++j) {
    const int arow = wid * 32 + j * 8 + (lane >> 3);
    aptr[j] = h + (size_t)(rslot[arow] & 0x3fffffff) * IDIM + aswz;
  }

  // B staging: 32 fp32 per thread
  const int brow = tid >> 1;
  const int bcb = (tid & 1) * 4;
  const int bswz = brow & 7;
  const float* bsrc = wd + (size_t)e * DDIM * IDIM + (size_t)(n0 + brow) * IDIM + bcb * 8;

  const int wr = wid >> 1, wc = wid & 1;
  const int fr = lane & 15;
  const int kc = lane >> 4;
  const int rsw = fr & 7;

  f32x4 acc[4][4] = {};

  // prologue
#pragma unroll
  for (int j = 0; j < 4; ++j) gload16(aptr[j], &A[0][wid * 32][0] + j * 512);
  float4 pb4[8];
#pragma unroll
  for (int q = 0; q < 8; ++q) pb4[q] = *(const float4*)(bsrc + q * 4);

#pragma unroll 2
  for (int t = 0; t < 88; ++t) {
    const int cur = t & 1;
    const int kp = (t < 87) ? (t + 1) * 64 : 87 * 64;

#pragma unroll
    for (int j = 0; j < 4; ++j) gload16(aptr[j] + kp, &A[cur ^ 1][wid * 32][0] + j * 512);
    float4 nb4[8];
#pragma unroll
    for (int q = 0; q < 8; ++q) nb4[q] = *(const float4*)(bsrc + kp + q * 4);
    __builtin_amdgcn_sched_barrier(0);
#pragma unroll
    for (int qq = 0; qq < 4; ++qq)
      *(u16x8*)&B[brow][((bcb + qq) ^ bswz) * 8] = cvt8(pb4[qq * 2], pb4[qq * 2 + 1]);
    PIPE_BAR1();

    __builtin_amdgcn_s_setprio(1);
#pragma unroll
    for (int kk = 0; kk < 2; ++kk) {
      bf16x8 a[4], b[4];
      const int cs = ((kk * 4 + kc) ^ rsw) * 8;
#pragma unroll
      for (int mf = 0; mf < 4; ++mf)
        a[mf] = *(const bf16x8*)&A[cur][wr * 64 + mf * 16 + fr][cs];
#pragma unroll
      for (int nf = 0; nf < 4; ++nf)
        b[nf] = *(const bf16x8*)&B[wc * 64 + nf * 16 + fr][cs];
#pragma unroll
      for (int mf = 0; mf < 4; ++mf)
#pragma unroll
        for (int nf = 0; nf < 4; ++nf)
          acc[mf][nf] = __builtin_amdgcn_mfma_f32_16x16x32_bf16(a[mf], b[nf], acc[mf][nf], 0, 0, 0);
    }
    __builtin_amdgcn_s_setprio(0);

    PIPE_BAR2();

#pragma unroll
    for (int q = 0; q < 8; ++q) pb4[q] = nb4[q];
  }

#pragma unroll
  for (int mf = 0; mf < 4; ++mf)
#pragma unroll
    for (int j = 0; j < 4; ++j) {
      const int r = wr * 64 + mf * 16 + (lane >> 4) * 4 + j;
      const int s = rslot[r];
      if (!(s & 0x40000000)) {
        const int t2 = s >> 1;
        const float w = rw[r];
#pragma unroll
        for (int nf = 0; nf < 4; ++nf)
          atomicAdd(out + (size_t)t2 * DDIM + n0 + wc * 64 + nf * 16 + fr,
                    acc[mf][nf][j] * w);
      }
    }
}

extern "C" void kernel_launch(void* const* d_in, const int* in_sizes, int n_in,
                              void* d_out, int out_size, void* d_ws, size_t ws_size,
                              hipStream_t stream) {
  const float* x  = (const float*)d_in[0];
  const float* gw = (const float*)d_in[1];
  const float* wg = (const float*)d_in[2];
  const float* wu = (const float*)d_in[3];
  const float* wd = (const float*)d_in[4];
  float* out = (float*)d_out;

  char* ws = (char*)d_ws;
  unsigned short* xbf = (unsigned short*)ws;                       // 8,388,608 B
  unsigned short* h   = (unsigned short*)(ws + 8388608);           // 46,137,344 B
  int*   slots = (int*)(ws + 8388608 + 46137344);                  // 65,536 B
  float* wts   = (float*)(ws + 8388608 + 46137344 + 65536);        // 65,536 B
  int*   cnt   = (int*)(ws + 8388608 + 46137344 + 131072);         // 32 B

  hipMemsetAsync(cnt, 0, NEXP * sizeof(int), stream);
  hipMemsetAsync(d_out, 0, (size_t)TTOK * DDIM * sizeof(float), stream);

  router_kernel<<<TTOK / 4, 256, 0, stream>>>(x, gw, xbf, cnt, slots, wts);
  gateup_kernel<<<11264, 256, 0, stream>>>(xbf, wg, wu, cnt, slots, h);
  down_kernel<<<2048, 256, 0, stream>>>(h, wd, cnt, slots, wts, out);
}

// Round 5
// 889.877 us; speedup vs baseline: 1.3474x; 1.3474x over previous
//
#include <hip/hip_runtime.h>
#include <hip/hip_bf16.h>
#include <stdint.h>

#define TTOK 2048
#define DDIM 2048
#define IDIM 5632
#define NEXP 8

typedef __attribute__((ext_vector_type(8))) short bf16x8;
typedef __attribute__((ext_vector_type(4))) float f32x4;
typedef __attribute__((ext_vector_type(8))) unsigned short u16x8;
typedef __attribute__((ext_vector_type(4))) unsigned short u16x4;

__device__ __forceinline__ unsigned short f2bf(float f) {
  union { float f; uint32_t u; } v; v.f = f;
  uint32_t u = v.u + 0x7fffu + ((v.u >> 16) & 1u);
  return (unsigned short)(u >> 16);
}

__device__ __forceinline__ uint32_t fbits(float f) {
  union { float f; uint32_t u; } v; v.f = f; return v.u;
}

// truncating packed f32x2 -> bf16x2 via v_perm_b32 (1 inst per 2 values)
__device__ __forceinline__ u16x8 cvt8t(float4 a, float4 b) {
  union { u16x8 v; uint32_t w[4]; } r;
  r.w[0] = __builtin_amdgcn_perm(fbits(a.y), fbits(a.x), 0x07060302);
  r.w[1] = __builtin_amdgcn_perm(fbits(a.w), fbits(a.z), 0x07060302);
  r.w[2] = __builtin_amdgcn_perm(fbits(b.y), fbits(b.x), 0x07060302);
  r.w[3] = __builtin_amdgcn_perm(fbits(b.w), fbits(b.z), 0x07060302);
  return r.v;
}

typedef __attribute__((address_space(3))) void lds_t;
typedef const __attribute__((address_space(1))) void gbl_t;
__device__ __forceinline__ void gload16(const void* g, void* l) {
  __builtin_amdgcn_global_load_lds((gbl_t*)g, (lds_t*)l, 16, 0, 0);
}

// counted-vmcnt pipeline barriers: 12 = 4 A-gloads + 8 B reg-loads stay in flight
#define PIPE_BAR1() asm volatile("s_waitcnt vmcnt(12) lgkmcnt(0)\n\ts_barrier" ::: "memory")
#define PIPE_BAR2() asm volatile("s_barrier" ::: "memory")

// ---------------- router: logits, top-2, softmax, expert lists, x->bf16 ----------------
__global__ __launch_bounds__(256) void router_kernel(
    const float* __restrict__ x, const float* __restrict__ gw,
    unsigned short* __restrict__ xbf,
    int* __restrict__ cnt, int* __restrict__ slots, float* __restrict__ wts)
{
  const int lane = threadIdx.x & 63;
  const int t = (blockIdx.x * blockDim.x + threadIdx.x) >> 6;  // one wave per token
  const float* xr = x + (size_t)t * DDIM;
  float acc[NEXP];
#pragma unroll
  for (int e = 0; e < NEXP; ++e) acc[e] = 0.f;
#pragma unroll
  for (int it = 0; it < DDIM / 256; ++it) {
    const int d = (it * 64 + lane) * 4;
    const float4 xv = *(const float4*)(xr + d);
    u16x4 xb; xb[0]=f2bf(xv.x); xb[1]=f2bf(xv.y); xb[2]=f2bf(xv.z); xb[3]=f2bf(xv.w);
    *(u16x4*)(xbf + (size_t)t * DDIM + d) = xb;
#pragma unroll
    for (int e = 0; e < NEXP; ++e) {
      const float4 gv = *(const float4*)(gw + (size_t)e * DDIM + d);
      acc[e] += xv.x*gv.x + xv.y*gv.y + xv.z*gv.z + xv.w*gv.w;
    }
  }
#pragma unroll
  for (int e = 0; e < NEXP; ++e) {
    float v = acc[e];
#pragma unroll
    for (int off = 32; off > 0; off >>= 1) v += __shfl_xor(v, off);
    acc[e] = v;
  }
  if (lane == 0) {
    int i0 = 0; float v0 = acc[0];
#pragma unroll
    for (int e = 1; e < NEXP; ++e) if (acc[e] > v0) { v0 = acc[e]; i0 = e; }
    int i1 = -1; float v1 = -3.4e38f;
#pragma unroll
    for (int e = 0; e < NEXP; ++e) { if (e == i0) continue; if (acc[e] > v1) { v1 = acc[e]; i1 = e; } }
    const float e1 = __expf(v1 - v0);
    const float w0 = 1.f / (1.f + e1);
    const float w1 = e1 / (1.f + e1);
    const int p0 = atomicAdd(&cnt[i0], 1);
    slots[i0 * TTOK + p0] = t * 2;     wts[i0 * TTOK + p0] = w0;
    const int p1 = atomicAdd(&cnt[i1], 1);
    slots[i1 * TTOK + p1] = t * 2 + 1; wts[i1 * TTOK + p1] = w1;
  }
}

// ---------------- plan: compact (expert, mt) tile list ----------------
__global__ void plan_kernel(const int* __restrict__ cnt,
                            int* __restrict__ tilemap, int* __restrict__ ntiles)
{
  if (threadIdx.x == 0 && blockIdx.x == 0) {
    int n = 0;
#pragma unroll
    for (int e = 0; e < NEXP; ++e) {
      const int nt = (cnt[e] + 127) >> 7;
      for (int m = 0; m < nt; ++m) tilemap[n++] = (e << 8) | m;
    }
    ntiles[0] = n;   // <= 39
  }
}

// chunk swizzle: 16B chunk c of row r stored at chunk c ^ (r & 7)

// ---------------- gate+up grouped GEMM: 128M x 64N x 2 mats, BK=64, counted-vmcnt pipeline ----------------
__global__ __launch_bounds__(256) void gateup_kernel(
    const unsigned short* __restrict__ xbf,
    const float* __restrict__ wg, const float* __restrict__ wu,
    const int* __restrict__ cnt, const int* __restrict__ slots,
    const int* __restrict__ tilemap, const int* __restrict__ ntiles,
    unsigned short* __restrict__ h)
{
  // grid 3520 = 40 tiles x 88 n-panels; XCD swizzle, tile fastest in chunk
  const int flat = (blockIdx.x & 7) * 440 + (blockIdx.x >> 3);
  const int ti = flat % 40;
  if (ti >= ntiles[0]) return;
  const int em = tilemap[ti];
  const int e = em >> 8;
  const int mt = em & 255;
  const int n0 = (flat / 40) * 64;
  const int count = cnt[e];
  const int m0 = mt * 128;

  __shared__ unsigned short A[2][128][64];   // dbuf, 32 KB
  __shared__ unsigned short Bg[64][64];      // single buf, 8 KB
  __shared__ unsigned short Bu[64][64];      // single buf, 8 KB
  __shared__ int rslot[128];
  __shared__ int rtok[128];

  const int tid = threadIdx.x;
  const int lane = tid & 63;
  const int wid = tid >> 6;

  if (tid < 128) {
    const int idx = m0 + tid;
    const int safe = slots[e * TTOK + m0];
    const int s = (idx < count) ? slots[e * TTOK + idx] : safe;
    rslot[tid] = (idx < count) ? s : -1;
    rtok[tid] = s >> 1;
  }
  __syncthreads();

  // A gather: per-lane global src, chunk pre-swizzled so linear gload_lds dest = swizzled LDS
  const int aswz = ((lane & 7) ^ ((lane >> 3) & 7)) * 8;
  const unsigned short* aptr[4];
#pragma unroll
  for (int j = 0; j < 4; ++j) {
    const int arow = wid * 32 + j * 8 + (lane >> 3);
    aptr[j] = xbf + (size_t)rtok[arow] * DDIM + aswz;
  }

  // B staging addresses: 16 fp32 per thread per matrix
  const int brow = tid >> 2;
  const int bcb = (tid & 3) * 2;      // base 16B-chunk index (of 8)
  const int bswz = brow & 7;
  const size_t wboff = (size_t)e * IDIM * DDIM + (size_t)(n0 + brow) * DDIM + bcb * 8;
  const float* gsrc = wg + wboff;
  const float* usrc = wu + wboff;

  const int wr = wid >> 1, wc = wid & 1;
  const int fr = lane & 15;
  const int kc = lane >> 4;
  const int rsw = fr & 7;

  f32x4 accg[4][2] = {};
  f32x4 accu[4][2] = {};

  // prologue: issue A(0) [4 vmem], load B(0) regs [8 vmem]
#pragma unroll
  for (int j = 0; j < 4; ++j) gload16(aptr[j], &A[0][wid * 32][0] + j * 512);
  float4 pg4[4], pu4[4];
#pragma unroll
  for (int q = 0; q < 4; ++q) { pg4[q] = *(const float4*)(gsrc + q * 4); pu4[q] = *(const float4*)(usrc + q * 4); }

#pragma unroll 2
  for (int t = 0; t < 32; ++t) {
    const int cur = t & 1;
    const int kp = (t < 31) ? (t + 1) * 64 : 31 * 64;  // clamped prefetch offset

    // step 1: A(t+1) direct-to-LDS into bufA[cur^1]
#pragma unroll
    for (int j = 0; j < 4; ++j) gload16(aptr[j] + kp, &A[cur ^ 1][wid * 32][0] + j * 512);
    // step 2: B(t+1) into regs
    float4 ng4[4], nu4[4];
#pragma unroll
    for (int q = 0; q < 4; ++q) { ng4[q] = *(const float4*)(gsrc + kp + q * 4); nu4[q] = *(const float4*)(usrc + kp + q * 4); }
    __builtin_amdgcn_sched_barrier(0);
    // step 3: pack + ds_write B(t)
#pragma unroll
    for (int qq = 0; qq < 2; ++qq) {
      const int oc = ((bcb + qq) ^ bswz) * 8;
      *(u16x8*)&Bg[brow][oc] = cvt8t(pg4[qq * 2], pg4[qq * 2 + 1]);
      *(u16x8*)&Bu[brow][oc] = cvt8t(pu4[qq * 2], pu4[qq * 2 + 1]);
    }
    // barrier #1: A(t) done (older than the 12 in flight), B(t) ds_writes visible
    PIPE_BAR1();

    __builtin_amdgcn_s_setprio(1);
#pragma unroll
    for (int kk = 0; kk < 2; ++kk) {
      bf16x8 a[4], bg[2], bu[2];
      const int cs = ((kk * 4 + kc) ^ rsw) * 8;
#pragma unroll
      for (int mf = 0; mf < 4; ++mf)
        a[mf] = *(const bf16x8*)&A[cur][wr * 64 + mf * 16 + fr][cs];
#pragma unroll
      for (int nf = 0; nf < 2; ++nf) {
        bg[nf] = *(const bf16x8*)&Bg[wc * 32 + nf * 16 + fr][cs];
        bu[nf] = *(const bf16x8*)&Bu[wc * 32 + nf * 16 + fr][cs];
      }
#pragma unroll
      for (int mf = 0; mf < 4; ++mf)
#pragma unroll
        for (int nf = 0; nf < 2; ++nf) {
          accg[mf][nf] = __builtin_amdgcn_mfma_f32_16x16x32_bf16(a[mf], bg[nf], accg[mf][nf], 0, 0, 0);
          accu[mf][nf] = __builtin_amdgcn_mfma_f32_16x16x32_bf16(a[mf], bu[nf], accu[mf][nf], 0, 0, 0);
        }
    }
    __builtin_amdgcn_s_setprio(0);

    // barrier #2: all waves done reading this tile's LDS before next body's writes
    PIPE_BAR2();

    // rotate B regs
#pragma unroll
    for (int q = 0; q < 4; ++q) { pg4[q] = ng4[q]; pu4[q] = nu4[q]; }
  }

#pragma unroll
  for (int mf = 0; mf < 4; ++mf)
#pragma unroll
    for (int nf = 0; nf < 2; ++nf)
#pragma unroll
      for (int j = 0; j < 4; ++j) {
        const int r = wr * 64 + mf * 16 + (lane >> 4) * 4 + j;
        const int s = rslot[r];
        if (s >= 0) {
          const float g = accg[mf][nf][j];
          const float u = accu[mf][nf][j];
          const float hv = g / (1.f + __expf(-g)) * u;
          h[(size_t)s * IDIM + n0 + wc * 32 + nf * 16 + fr] = f2bf(hv);
        }
      }
}

// ---------------- down grouped GEMM: 128M x 128N, K-split x2, counted-vmcnt pipeline ----------------
__global__ __launch_bounds__(256) void down_kernel(
    const unsigned short* __restrict__ h,
    const float* __restrict__ wd,
    const int* __restrict__ cnt, const int* __restrict__ slots,
    const float* __restrict__ wts,
    const int* __restrict__ tilemap, const int* __restrict__ ntiles,
    float* __restrict__ out)
{
  // grid 1280 = 40 tiles x 16 n-panels x 2 k-splits; XCD swizzle, tile fastest
  const int flat = (blockIdx.x & 7) * 160 + (blockIdx.x >> 3);
  const int ti = flat % 40;
  if (ti >= ntiles[0]) return;
  const int em = tilemap[ti];
  const int e = em >> 8;
  const int mt = em & 255;
  const int r2 = flat / 40;
  const int n0 = (r2 & 15) * 128;
  const int ks = r2 >> 4;           // k-split half
  const int kbase = ks * (IDIM / 2);
  const int count = cnt[e];
  const int m0 = mt * 128;

  __shared__ unsigned short A[2][128][64];   // dbuf, 32 KB
  __shared__ unsigned short B[128][64];      // single buf, 16 KB
  __shared__ int rslot[128];
  __shared__ float rw[128];

  const int tid = threadIdx.x;
  const int lane = tid & 63;
  const int wid = tid >> 6;

  if (tid < 128) {
    const int idx = m0 + tid;
    const int safe = slots[e * TTOK + m0];
    const int s = (idx < count) ? slots[e * TTOK + idx] : safe;
    rslot[tid] = (idx < count) ? s : (safe | 0x40000000);
    rw[tid] = (idx < count) ? wts[e * TTOK + idx] : 0.f;
  }
  __syncthreads();

  const int aswz = ((lane & 7) ^ ((lane >> 3) & 7)) * 8;
  const unsigned short* aptr[4];
#pragma unroll
  for (int j = 0; j < 4; ++j) {
    const int arow = wid * 32 + j * 8 + (lane >> 3);
    aptr[j] = h + (size_t)(rslot[arow] & 0x3fffffff) * IDIM + kbase + aswz;
  }

  // B staging: 32 fp32 per thread
  const int brow = tid >> 1;
  const int bcb = (tid & 1) * 4;
  const int bswz = brow & 7;
  const float* bsrc = wd + (size_t)e * DDIM * IDIM + (size_t)(n0 + brow) * IDIM + kbase + bcb * 8;

  const int wr = wid >> 1, wc = wid & 1;
  const int fr = lane & 15;
  const int kc = lane >> 4;
  const int rsw = fr & 7;

  f32x4 acc[4][4] = {};

  // prologue
#pragma unroll
  for (int j = 0; j < 4; ++j) gload16(aptr[j], &A[0][wid * 32][0] + j * 512);
  float4 pb4[8];
#pragma unroll
  for (int q = 0; q < 8; ++q) pb4[q] = *(const float4*)(bsrc + q * 4);

#pragma unroll 2
  for (int t = 0; t < 44; ++t) {
    const int cur = t & 1;
    const int kp = (t < 43) ? (t + 1) * 64 : 43 * 64;

#pragma unroll
    for (int j = 0; j < 4; ++j) gload16(aptr[j] + kp, &A[cur ^ 1][wid * 32][0] + j * 512);
    float4 nb4[8];
#pragma unroll
    for (int q = 0; q < 8; ++q) nb4[q] = *(const float4*)(bsrc + kp + q * 4);
    __builtin_amdgcn_sched_barrier(0);
#pragma unroll
    for (int qq = 0; qq < 4; ++qq)
      *(u16x8*)&B[brow][((bcb + qq) ^ bswz) * 8] = cvt8t(pb4[qq * 2], pb4[qq * 2 + 1]);
    PIPE_BAR1();

    __builtin_amdgcn_s_setprio(1);
#pragma unroll
    for (int kk = 0; kk < 2; ++kk) {
      bf16x8 a[4], b[4];
      const int cs = ((kk * 4 + kc) ^ rsw) * 8;
#pragma unroll
      for (int mf = 0; mf < 4; ++mf)
        a[mf] = *(const bf16x8*)&A[cur][wr * 64 + mf * 16 + fr][cs];
#pragma unroll
      for (int nf = 0; nf < 4; ++nf)
        b[nf] = *(const bf16x8*)&B[wc * 64 + nf * 16 + fr][cs];
#pragma unroll
      for (int mf = 0; mf < 4; ++mf)
#pragma unroll
        for (int nf = 0; nf < 4; ++nf)
          acc[mf][nf] = __builtin_amdgcn_mfma_f32_16x16x32_bf16(a[mf], b[nf], acc[mf][nf], 0, 0, 0);
    }
    __builtin_amdgcn_s_setprio(0);

    PIPE_BAR2();

#pragma unroll
    for (int q = 0; q < 8; ++q) pb4[q] = nb4[q];
  }

#pragma unroll
  for (int mf = 0; mf < 4; ++mf)
#pragma unroll
    for (int j = 0; j < 4; ++j) {
      const int r = wr * 64 + mf * 16 + (lane >> 4) * 4 + j;
      const int s = rslot[r];
      if (!(s & 0x40000000)) {
        const int t2 = s >> 1;
        const float w = rw[r];
#pragma unroll
        for (int nf = 0; nf < 4; ++nf)
          atomicAdd(out + (size_t)t2 * DDIM + n0 + wc * 64 + nf * 16 + fr,
                    acc[mf][nf][j] * w);
      }
    }
}

extern "C" void kernel_launch(void* const* d_in, const int* in_sizes, int n_in,
                              void* d_out, int out_size, void* d_ws, size_t ws_size,
                              hipStream_t stream) {
  const float* x  = (const float*)d_in[0];
  const float* gw = (const float*)d_in[1];
  const float* wg = (const float*)d_in[2];
  const float* wu = (const float*)d_in[3];
  const float* wd = (const float*)d_in[4];
  float* out = (float*)d_out;

  char* ws = (char*)d_ws;
  unsigned short* xbf = (unsigned short*)ws;                       // 8,388,608 B
  unsigned short* h   = (unsigned short*)(ws + 8388608);           // 46,137,344 B
  int*   slots = (int*)(ws + 8388608 + 46137344);                  // 65,536 B
  float* wts   = (float*)(ws + 8388608 + 46137344 + 65536);        // 65,536 B
  int*   cnt   = (int*)(ws + 8388608 + 46137344 + 131072);         // 32 B
  int*   tmap  = (int*)(ws + 8388608 + 46137344 + 131072 + 32);    // 256 B
  int*   ntl   = (int*)(ws + 8388608 + 46137344 + 131072 + 288);   // 4 B

  hipMemsetAsync(cnt, 0, NEXP * sizeof(int), stream);
  hipMemsetAsync(d_out, 0, (size_t)TTOK * DDIM * sizeof(float), stream);

  router_kernel<<<TTOK / 4, 256, 0, stream>>>(x, gw, xbf, cnt, slots, wts);
  plan_kernel<<<1, 64, 0, stream>>>(cnt, tmap, ntl);
  gateup_kernel<<<3520, 256, 0, stream>>>(xbf, wg, wu, cnt, slots, tmap, ntl, h);
  down_kernel<<<1280, 256, 0, stream>>>(h, wd, cnt, slots, wts, tmap, ntl, out);
}

// Round 6
// 874.170 us; speedup vs baseline: 1.3716x; 1.0180x over previous
//
#include <hip/hip_runtime.h>
#include <hip/hip_bf16.h>
#include <stdint.h>

#define TTOK 2048
#define DDIM 2048
#define IDIM 5632
#define NEXP 8

typedef __attribute__((ext_vector_type(8))) short bf16x8;
typedef __attribute__((ext_vector_type(4))) float f32x4;
typedef __attribute__((ext_vector_type(8))) unsigned short u16x8;
typedef __attribute__((ext_vector_type(4))) unsigned short u16x4;

__device__ __forceinline__ unsigned short f2bf(float f) {
  union { float f; uint32_t u; } v; v.f = f;
  uint32_t u = v.u + 0x7fffu + ((v.u >> 16) & 1u);
  return (unsigned short)(u >> 16);
}

__device__ __forceinline__ uint32_t fbits(float f) {
  union { float f; uint32_t u; } v; v.f = f; return v.u;
}

// truncating packed f32x2 -> bf16x2 via v_perm_b32 (1 inst per 2 values)
__device__ __forceinline__ u16x8 cvt8t(float4 a, float4 b) {
  union { u16x8 v; uint32_t w[4]; } r;
  r.w[0] = __builtin_amdgcn_perm(fbits(a.y), fbits(a.x), 0x07060302);
  r.w[1] = __builtin_amdgcn_perm(fbits(a.w), fbits(a.z), 0x07060302);
  r.w[2] = __builtin_amdgcn_perm(fbits(b.y), fbits(b.x), 0x07060302);
  r.w[3] = __builtin_amdgcn_perm(fbits(b.w), fbits(b.z), 0x07060302);
  return r.v;
}

typedef __attribute__((address_space(3))) void lds_t;
typedef const __attribute__((address_space(1))) void gbl_t;
__device__ __forceinline__ void gload16(const void* g, void* l) {
  __builtin_amdgcn_global_load_lds((gbl_t*)g, (lds_t*)l, 16, 0, 0);
}

// BAR1: wait A(t) done (20 newer vmem ops stay in flight: 8 B(t+1) + 4 A(t+1) + 8 B(t+2)),
//       drain lgkm so B(t) ds_writes are visible, then sync.
#define PIPE_BAR1() asm volatile("s_waitcnt vmcnt(20) lgkmcnt(0)\n\ts_barrier" ::: "memory")
#define PIPE_BAR2() asm volatile("s_barrier" ::: "memory")

// ---------------- router: logits, top-2, softmax, expert lists, x->bf16 ----------------
__global__ __launch_bounds__(256) void router_kernel(
    const float* __restrict__ x, const float* __restrict__ gw,
    unsigned short* __restrict__ xbf,
    int* __restrict__ cnt, int* __restrict__ slots, float* __restrict__ wts)
{
  const int lane = threadIdx.x & 63;
  const int t = (blockIdx.x * blockDim.x + threadIdx.x) >> 6;  // one wave per token
  const float* xr = x + (size_t)t * DDIM;
  float acc[NEXP];
#pragma unroll
  for (int e = 0; e < NEXP; ++e) acc[e] = 0.f;
#pragma unroll
  for (int it = 0; it < DDIM / 256; ++it) {
    const int d = (it * 64 + lane) * 4;
    const float4 xv = *(const float4*)(xr + d);
    u16x4 xb; xb[0]=f2bf(xv.x); xb[1]=f2bf(xv.y); xb[2]=f2bf(xv.z); xb[3]=f2bf(xv.w);
    *(u16x4*)(xbf + (size_t)t * DDIM + d) = xb;
#pragma unroll
    for (int e = 0; e < NEXP; ++e) {
      const float4 gv = *(const float4*)(gw + (size_t)e * DDIM + d);
      acc[e] += xv.x*gv.x + xv.y*gv.y + xv.z*gv.z + xv.w*gv.w;
    }
  }
#pragma unroll
  for (int e = 0; e < NEXP; ++e) {
    float v = acc[e];
#pragma unroll
    for (int off = 32; off > 0; off >>= 1) v += __shfl_xor(v, off);
    acc[e] = v;
  }
  if (lane == 0) {
    int i0 = 0; float v0 = acc[0];
#pragma unroll
    for (int e = 1; e < NEXP; ++e) if (acc[e] > v0) { v0 = acc[e]; i0 = e; }
    int i1 = -1; float v1 = -3.4e38f;
#pragma unroll
    for (int e = 0; e < NEXP; ++e) { if (e == i0) continue; if (acc[e] > v1) { v1 = acc[e]; i1 = e; } }
    const float e1 = __expf(v1 - v0);
    const float w0 = 1.f / (1.f + e1);
    const float w1 = e1 / (1.f + e1);
    const int p0 = atomicAdd(&cnt[i0], 1);
    slots[i0 * TTOK + p0] = t * 2;     wts[i0 * TTOK + p0] = w0;
    const int p1 = atomicAdd(&cnt[i1], 1);
    slots[i1 * TTOK + p1] = t * 2 + 1; wts[i1 * TTOK + p1] = w1;
  }
}

// ---------------- plan: compact (expert, mt) tile list ----------------
__global__ void plan_kernel(const int* __restrict__ cnt,
                            int* __restrict__ tilemap, int* __restrict__ ntiles)
{
  if (threadIdx.x == 0 && blockIdx.x == 0) {
    int n = 0;
#pragma unroll
    for (int e = 0; e < NEXP; ++e) {
      const int nt = (cnt[e] + 127) >> 7;
      for (int m = 0; m < nt; ++m) tilemap[n++] = (e << 8) | m;
    }
    ntiles[0] = n;   // <= 39
  }
}

// chunk swizzle: 16B chunk c of row r stored at chunk c ^ (r & 7)

// ---------------- gate+up grouped GEMM: 128M x 64N x 2 mats, BK=64, depth-2 B prefetch ----------------
__global__ __launch_bounds__(256) void gateup_kernel(
    const unsigned short* __restrict__ xbf,
    const float* __restrict__ wg, const float* __restrict__ wu,
    const int* __restrict__ cnt, const int* __restrict__ slots,
    const int* __restrict__ tilemap, const int* __restrict__ ntiles,
    unsigned short* __restrict__ h)
{
  // grid 3520 = 40 tiles x 88 n-panels; XCD swizzle, tile fastest in chunk
  const int flat = (blockIdx.x & 7) * 440 + (blockIdx.x >> 3);
  const int ti = flat % 40;
  if (ti >= ntiles[0]) return;
  const int em = tilemap[ti];
  const int e = em >> 8;
  const int mt = em & 255;
  const int n0 = (flat / 40) * 64;
  const int count = cnt[e];
  const int m0 = mt * 128;

  __shared__ unsigned short A[2][128][64];   // dbuf, 32 KB
  __shared__ unsigned short Bg[64][64];      // single buf, 8 KB
  __shared__ unsigned short Bu[64][64];      // single buf, 8 KB
  __shared__ int rslot[128];
  __shared__ int rtok[128];

  const int tid = threadIdx.x;
  const int lane = tid & 63;
  const int wid = tid >> 6;

  if (tid < 128) {
    const int idx = m0 + tid;
    const int safe = slots[e * TTOK + m0];
    const int s = (idx < count) ? slots[e * TTOK + idx] : safe;
    rslot[tid] = (idx < count) ? s : -1;
    rtok[tid] = s >> 1;
  }
  __syncthreads();

  // A gather: per-lane global src, chunk pre-swizzled so linear gload_lds dest = swizzled LDS
  const int aswz = ((lane & 7) ^ ((lane >> 3) & 7)) * 8;
  const unsigned short* aptr[4];
#pragma unroll
  for (int j = 0; j < 4; ++j) {
    const int arow = wid * 32 + j * 8 + (lane >> 3);
    aptr[j] = xbf + (size_t)rtok[arow] * DDIM + aswz;
  }

  // B staging addresses: 16 fp32 per thread per matrix
  const int brow = tid >> 2;
  const int bcb = (tid & 3) * 2;      // base 16B-chunk index (of 8)
  const int bswz = brow & 7;
  const size_t wboff = (size_t)e * IDIM * DDIM + (size_t)(n0 + brow) * DDIM + bcb * 8;
  const float* gsrc = wg + wboff;
  const float* usrc = wu + wboff;

  const int wr = wid >> 1, wc = wid & 1;
  const int fr = lane & 15;
  const int kc = lane >> 4;
  const int rsw = fr & 7;

  f32x4 accg[4][2] = {};
  f32x4 accu[4][2] = {};

  // prologue: issue A(0) [4 vmem]; load B(0)->stage0, B(1)->stage1 [16 vmem]
  float4 Pg[2][4], Pu[2][4];
#pragma unroll
  for (int j = 0; j < 4; ++j) gload16(aptr[j], &A[0][wid * 32][0] + j * 512);
#pragma unroll
  for (int q = 0; q < 4; ++q) { Pg[0][q] = *(const float4*)(gsrc + q * 4);      Pu[0][q] = *(const float4*)(usrc + q * 4); }
#pragma unroll
  for (int q = 0; q < 4; ++q) { Pg[1][q] = *(const float4*)(gsrc + 64 + q * 4); Pu[1][q] = *(const float4*)(usrc + 64 + q * 4); }

#pragma unroll 2
  for (int t = 0; t < 32; ++t) {
    const int cur = t & 1;
    const int st = t & 1;                                   // B stage consumed this iter
    const int kp  = (t < 31) ? (t + 1) * 64 : 31 * 64;      // A prefetch offset
    const int kp2 = (t + 2 <= 31) ? (t + 2) * 64 : 31 * 64; // B prefetch offset

    // step 1: A(t+1) direct-to-LDS into bufA[cur^1]
#pragma unroll
    for (int j = 0; j < 4; ++j) gload16(aptr[j] + kp, &A[cur ^ 1][wid * 32][0] + j * 512);
    __builtin_amdgcn_sched_barrier(0);
    // step 2: cvt + ds_write B(t) (loaded 2 iterations ago; compiler inserts counted vmcnt)
#pragma unroll
    for (int qq = 0; qq < 2; ++qq) {
      const int oc = ((bcb + qq) ^ bswz) * 8;
      *(u16x8*)&Bg[brow][oc] = cvt8t(Pg[st][qq * 2], Pg[st][qq * 2 + 1]);
      *(u16x8*)&Bu[brow][oc] = cvt8t(Pu[st][qq * 2], Pu[st][qq * 2 + 1]);
    }
    // step 3: B(t+2) into the just-freed stage regs
#pragma unroll
    for (int q = 0; q < 4; ++q) { Pg[st][q] = *(const float4*)(gsrc + kp2 + q * 4); Pu[st][q] = *(const float4*)(usrc + kp2 + q * 4); }
    // barrier #1: A(t) done (20 newer ops in flight), B(t) ds_writes visible
    PIPE_BAR1();

    __builtin_amdgcn_s_setprio(1);
#pragma unroll
    for (int kk = 0; kk < 2; ++kk) {
      bf16x8 a[4], bg[2], bu[2];
      const int cs = ((kk * 4 + kc) ^ rsw) * 8;
#pragma unroll
      for (int mf = 0; mf < 4; ++mf)
        a[mf] = *(const bf16x8*)&A[cur][wr * 64 + mf * 16 + fr][cs];
#pragma unroll
      for (int nf = 0; nf < 2; ++nf) {
        bg[nf] = *(const bf16x8*)&Bg[wc * 32 + nf * 16 + fr][cs];
        bu[nf] = *(const bf16x8*)&Bu[wc * 32 + nf * 16 + fr][cs];
      }
#pragma unroll
      for (int mf = 0; mf < 4; ++mf)
#pragma unroll
        for (int nf = 0; nf < 2; ++nf) {
          accg[mf][nf] = __builtin_amdgcn_mfma_f32_16x16x32_bf16(a[mf], bg[nf], accg[mf][nf], 0, 0, 0);
          accu[mf][nf] = __builtin_amdgcn_mfma_f32_16x16x32_bf16(a[mf], bu[nf], accu[mf][nf], 0, 0, 0);
        }
    }
    __builtin_amdgcn_s_setprio(0);

    // barrier #2: all waves done reading this tile's LDS before next body's writes
    PIPE_BAR2();
  }

#pragma unroll
  for (int mf = 0; mf < 4; ++mf)
#pragma unroll
    for (int nf = 0; nf < 2; ++nf)
#pragma unroll
      for (int j = 0; j < 4; ++j) {
        const int r = wr * 64 + mf * 16 + (lane >> 4) * 4 + j;
        const int s = rslot[r];
        if (s >= 0) {
          const float g = accg[mf][nf][j];
          const float u = accu[mf][nf][j];
          const float hv = g / (1.f + __expf(-g)) * u;
          h[(size_t)s * IDIM + n0 + wc * 32 + nf * 16 + fr] = f2bf(hv);
        }
      }
}

// ---------------- down grouped GEMM: 128M x 128N, K-split x2, depth-2 B prefetch ----------------
__global__ __launch_bounds__(256) void down_kernel(
    const unsigned short* __restrict__ h,
    const float* __restrict__ wd,
    const int* __restrict__ cnt, const int* __restrict__ slots,
    const float* __restrict__ wts,
    const int* __restrict__ tilemap, const int* __restrict__ ntiles,
    float* __restrict__ out)
{
  // grid 1280 = 40 tiles x 16 n-panels x 2 k-splits; XCD swizzle, tile fastest
  const int flat = (blockIdx.x & 7) * 160 + (blockIdx.x >> 3);
  const int ti = flat % 40;
  if (ti >= ntiles[0]) return;
  const int em = tilemap[ti];
  const int e = em >> 8;
  const int mt = em & 255;
  const int r2 = flat / 40;
  const int n0 = (r2 & 15) * 128;
  const int ks = r2 >> 4;           // k-split half
  const int kbase = ks * (IDIM / 2);
  const int count = cnt[e];
  const int m0 = mt * 128;

  __shared__ unsigned short A[2][128][64];   // dbuf, 32 KB
  __shared__ unsigned short B[128][64];      // single buf, 16 KB
  __shared__ int rslot[128];
  __shared__ float rw[128];

  const int tid = threadIdx.x;
  const int lane = tid & 63;
  const int wid = tid >> 6;

  if (tid < 128) {
    const int idx = m0 + tid;
    const int safe = slots[e * TTOK + m0];
    const int s = (idx < count) ? slots[e * TTOK + idx] : safe;
    rslot[tid] = (idx < count) ? s : (safe | 0x40000000);
    rw[tid] = (idx < count) ? wts[e * TTOK + idx] : 0.f;
  }
  __syncthreads();

  const int aswz = ((lane & 7) ^ ((lane >> 3) & 7)) * 8;
  const unsigned short* aptr[4];
#pragma unroll
  for (int j = 0; j < 4; ++j) {
    const int arow = wid * 32 + j * 8 + (lane >> 3);
    aptr[j] = h + (size_t)(rslot[arow] & 0x3fffffff) * IDIM + kbase + aswz;
  }

  // B staging: 32 fp32 per thread
  const int brow = tid >> 1;
  const int bcb = (tid & 1) * 4;
  const int bswz = brow & 7;
  const float* bsrc = wd + (size_t)e * DDIM * IDIM + (size_t)(n0 + brow) * IDIM + kbase + bcb * 8;

  const int wr = wid >> 1, wc = wid & 1;
  const int fr = lane & 15;
  const int kc = lane >> 4;
  const int rsw = fr & 7;

  f32x4 acc[4][4] = {};

  // prologue: issue A(0); load B(0)->stage0, B(1)->stage1
  float4 Pb[2][8];
#pragma unroll
  for (int j = 0; j < 4; ++j) gload16(aptr[j], &A[0][wid * 32][0] + j * 512);
#pragma unroll
  for (int q = 0; q < 8; ++q) Pb[0][q] = *(const float4*)(bsrc + q * 4);
#pragma unroll
  for (int q = 0; q < 8; ++q) Pb[1][q] = *(const float4*)(bsrc + 64 + q * 4);

#pragma unroll 2
  for (int t = 0; t < 44; ++t) {
    const int cur = t & 1;
    const int st = t & 1;
    const int kp  = (t < 43) ? (t + 1) * 64 : 43 * 64;
    const int kp2 = (t + 2 <= 43) ? (t + 2) * 64 : 43 * 64;

#pragma unroll
    for (int j = 0; j < 4; ++j) gload16(aptr[j] + kp, &A[cur ^ 1][wid * 32][0] + j * 512);
    __builtin_amdgcn_sched_barrier(0);
#pragma unroll
    for (int qq = 0; qq < 4; ++qq)
      *(u16x8*)&B[brow][((bcb + qq) ^ bswz) * 8] = cvt8t(Pb[st][qq * 2], Pb[st][qq * 2 + 1]);
#pragma unroll
    for (int q = 0; q < 8; ++q) Pb[st][q] = *(const float4*)(bsrc + kp2 + q * 4);
    PIPE_BAR1();

    __builtin_amdgcn_s_setprio(1);
#pragma unroll
    for (int kk = 0; kk < 2; ++kk) {
      bf16x8 a[4], b[4];
      const int cs = ((kk * 4 + kc) ^ rsw) * 8;
#pragma unroll
      for (int mf = 0; mf < 4; ++mf)
        a[mf] = *(const bf16x8*)&A[cur][wr * 64 + mf * 16 + fr][cs];
#pragma unroll
      for (int nf = 0; nf < 4; ++nf)
        b[nf] = *(const bf16x8*)&B[wc * 64 + nf * 16 + fr][cs];
#pragma unroll
      for (int mf = 0; mf < 4; ++mf)
#pragma unroll
        for (int nf = 0; nf < 4; ++nf)
          acc[mf][nf] = __builtin_amdgcn_mfma_f32_16x16x32_bf16(a[mf], b[nf], acc[mf][nf], 0, 0, 0);
    }
    __builtin_amdgcn_s_setprio(0);

    PIPE_BAR2();
  }

#pragma unroll
  for (int mf = 0; mf < 4; ++mf)
#pragma unroll
    for (int j = 0; j < 4; ++j) {
      const int r = wr * 64 + mf * 16 + (lane >> 4) * 4 + j;
      const int s = rslot[r];
      if (!(s & 0x40000000)) {
        const int t2 = s >> 1;
        const float w = rw[r];
#pragma unroll
        for (int nf = 0; nf < 4; ++nf)
          atomicAdd(out + (size_t)t2 * DDIM + n0 + wc * 64 + nf * 16 + fr,
                    acc[mf][nf][j] * w);
      }
    }
}

extern "C" void kernel_launch(void* const* d_in, const int* in_sizes, int n_in,
                              void* d_out, int out_size, void* d_ws, size_t ws_size,
                              hipStream_t stream) {
  const float* x  = (const float*)d_in[0];
  const float* gw = (const float*)d_in[1];
  const float* wg = (const float*)d_in[2];
  const float* wu = (const float*)d_in[3];
  const float* wd = (const float*)d_in[4];
  float* out = (float*)d_out;

  char* ws = (char*)d_ws;
  unsigned short* xbf = (unsigned short*)ws;                       // 8,388,608 B
  unsigned short* h   = (unsigned short*)(ws + 8388608);           // 46,137,344 B
  int*   slots = (int*)(ws + 8388608 + 46137344);                  // 65,536 B
  float* wts   = (float*)(ws + 8388608 + 46137344 + 65536);        // 65,536 B
  int*   cnt   = (int*)(ws + 8388608 + 46137344 + 131072);         // 32 B
  int*   tmap  = (int*)(ws + 8388608 + 46137344 + 131072 + 32);    // 256 B
  int*   ntl   = (int*)(ws + 8388608 + 46137344 + 131072 + 288);   // 4 B

  hipMemsetAsync(cnt, 0, NEXP * sizeof(int), stream);
  hipMemsetAsync(d_out, 0, (size_t)TTOK * DDIM * sizeof(float), stream);

  router_kernel<<<TTOK / 4, 256, 0, stream>>>(x, gw, xbf, cnt, slots, wts);
  plan_kernel<<<1, 64, 0, stream>>>(cnt, tmap, ntl);
  gateup_kernel<<<3520, 256, 0, stream>>>(xbf, wg, wu, cnt, slots, tmap, ntl, h);
  down_kernel<<<1280, 256, 0, stream>>>(h, wd, cnt, slots, wts, tmap, ntl, out);
}

// Round 7
// 858.184 us; speedup vs baseline: 1.3971x; 1.0186x over previous
//
#include <hip/hip_runtime.h>
#include <hip/hip_bf16.h>
#include <stdint.h>

#define TTOK 2048
#define DDIM 2048
#define IDIM 5632
#define NEXP 8

typedef __attribute__((ext_vector_type(8))) short bf16x8;
typedef __attribute__((ext_vector_type(4))) float f32x4;
typedef __attribute__((ext_vector_type(8))) unsigned short u16x8;
typedef __attribute__((ext_vector_type(4))) unsigned short u16x4;

__device__ __forceinline__ unsigned short f2bf(float f) {
  union { float f; uint32_t u; } v; v.f = f;
  uint32_t u = v.u + 0x7fffu + ((v.u >> 16) & 1u);
  return (unsigned short)(u >> 16);
}

__device__ __forceinline__ uint32_t fbits(float f) {
  union { float f; uint32_t u; } v; v.f = f; return v.u;
}

// truncating packed f32x2 -> bf16x2 via v_perm_b32 (1 inst per 2 values)
__device__ __forceinline__ u16x8 cvt8t(float4 a, float4 b) {
  union { u16x8 v; uint32_t w[4]; } r;
  r.w[0] = __builtin_amdgcn_perm(fbits(a.y), fbits(a.x), 0x07060302);
  r.w[1] = __builtin_amdgcn_perm(fbits(a.w), fbits(a.z), 0x07060302);
  r.w[2] = __builtin_amdgcn_perm(fbits(b.y), fbits(b.x), 0x07060302);
  r.w[3] = __builtin_amdgcn_perm(fbits(b.w), fbits(b.z), 0x07060302);
  return r.v;
}

typedef __attribute__((address_space(3))) void lds_t;
typedef const __attribute__((address_space(1))) void gbl_t;
__device__ __forceinline__ void gload16(const void* g, void* l) {
  __builtin_amdgcn_global_load_lds((gbl_t*)g, (lds_t*)l, 16, 0, 0);
}

// single barrier per K-step: retire the 4 A-gloads (oldest), keep 8 B reg-loads
// in flight; drain lgkm so this iter's ds_writes are visible after the barrier.
#define PIPE_WAIT_BAR() asm volatile("s_waitcnt vmcnt(8) lgkmcnt(0)\n\ts_barrier" ::: "memory")

// ---------------- router: logits, top-2, softmax, expert lists, x->bf16 ----------------
__global__ __launch_bounds__(256) void router_kernel(
    const float* __restrict__ x, const float* __restrict__ gw,
    unsigned short* __restrict__ xbf,
    int* __restrict__ cnt, int* __restrict__ slots, float* __restrict__ wts)
{
  const int lane = threadIdx.x & 63;
  const int t = (blockIdx.x * blockDim.x + threadIdx.x) >> 6;  // one wave per token
  const float* xr = x + (size_t)t * DDIM;
  float acc[NEXP];
#pragma unroll
  for (int e = 0; e < NEXP; ++e) acc[e] = 0.f;
#pragma unroll
  for (int it = 0; it < DDIM / 256; ++it) {
    const int d = (it * 64 + lane) * 4;
    const float4 xv = *(const float4*)(xr + d);
    u16x4 xb; xb[0]=f2bf(xv.x); xb[1]=f2bf(xv.y); xb[2]=f2bf(xv.z); xb[3]=f2bf(xv.w);
    *(u16x4*)(xbf + (size_t)t * DDIM + d) = xb;
#pragma unroll
    for (int e = 0; e < NEXP; ++e) {
      const float4 gv = *(const float4*)(gw + (size_t)e * DDIM + d);
      acc[e] += xv.x*gv.x + xv.y*gv.y + xv.z*gv.z + xv.w*gv.w;
    }
  }
#pragma unroll
  for (int e = 0; e < NEXP; ++e) {
    float v = acc[e];
#pragma unroll
    for (int off = 32; off > 0; off >>= 1) v += __shfl_xor(v, off);
    acc[e] = v;
  }
  if (lane == 0) {
    int i0 = 0; float v0 = acc[0];
#pragma unroll
    for (int e = 1; e < NEXP; ++e) if (acc[e] > v0) { v0 = acc[e]; i0 = e; }
    int i1 = -1; float v1 = -3.4e38f;
#pragma unroll
    for (int e = 0; e < NEXP; ++e) { if (e == i0) continue; if (acc[e] > v1) { v1 = acc[e]; i1 = e; } }
    const float e1 = __expf(v1 - v0);
    const float w0 = 1.f / (1.f + e1);
    const float w1 = e1 / (1.f + e1);
    const int p0 = atomicAdd(&cnt[i0], 1);
    slots[i0 * TTOK + p0] = t * 2;     wts[i0 * TTOK + p0] = w0;
    const int p1 = atomicAdd(&cnt[i1], 1);
    slots[i1 * TTOK + p1] = t * 2 + 1; wts[i1 * TTOK + p1] = w1;
  }
}

// ---------------- plan: compact (expert, mt) tile list ----------------
__global__ void plan_kernel(const int* __restrict__ cnt,
                            int* __restrict__ tilemap, int* __restrict__ ntiles)
{
  if (threadIdx.x == 0 && blockIdx.x == 0) {
    int n = 0;
#pragma unroll
    for (int e = 0; e < NEXP; ++e) {
      const int nt = (cnt[e] + 127) >> 7;
      for (int m = 0; m < nt; ++m) tilemap[n++] = (e << 8) | m;
    }
    ntiles[0] = n;   // <= 39
  }
}

// chunk swizzle: 16B chunk c of row r stored at chunk c ^ (r & 7)

// ---------------- gate+up grouped GEMM: 128M x 64N x 2 mats, BK=64, full dbuf, 1 barrier/iter ----------------
__global__ __launch_bounds__(256) void gateup_kernel(
    const unsigned short* __restrict__ xbf,
    const float* __restrict__ wg, const float* __restrict__ wu,
    const int* __restrict__ cnt, const int* __restrict__ slots,
    const int* __restrict__ tilemap, const int* __restrict__ ntiles,
    unsigned short* __restrict__ h)
{
  // grid 3520 = 40 tiles x 88 n-panels; XCD swizzle, tile fastest in chunk
  const int flat = (blockIdx.x & 7) * 440 + (blockIdx.x >> 3);
  const int ti = flat % 40;
  if (ti >= ntiles[0]) return;
  const int em = tilemap[ti];
  const int e = em >> 8;
  const int mt = em & 255;
  const int n0 = (flat / 40) * 64;
  const int count = cnt[e];
  const int m0 = mt * 128;

  __shared__ unsigned short A[2][128][64];    // dbuf, 32 KB
  __shared__ unsigned short Bg[2][64][64];    // dbuf, 16 KB
  __shared__ unsigned short Bu[2][64][64];    // dbuf, 16 KB
  __shared__ int rslot[128];
  __shared__ int rtok[128];

  const int tid = threadIdx.x;
  const int lane = tid & 63;
  const int wid = tid >> 6;

  if (tid < 128) {
    const int idx = m0 + tid;
    const int safe = slots[e * TTOK + m0];
    const int s = (idx < count) ? slots[e * TTOK + idx] : safe;
    rslot[tid] = (idx < count) ? s : -1;
    rtok[tid] = s >> 1;
  }
  __syncthreads();

  // A gather: per-lane global src, chunk pre-swizzled so linear gload_lds dest = swizzled LDS
  const int aswz = ((lane & 7) ^ ((lane >> 3) & 7)) * 8;
  const unsigned short* aptr[4];
#pragma unroll
  for (int j = 0; j < 4; ++j) {
    const int arow = wid * 32 + j * 8 + (lane >> 3);
    aptr[j] = xbf + (size_t)rtok[arow] * DDIM + aswz;
  }

  // B staging addresses: 16 fp32 per thread per matrix
  const int brow = tid >> 2;
  const int bcb = (tid & 3) * 2;      // base 16B-chunk index (of 8)
  const int bswz = brow & 7;
  const size_t wboff = (size_t)e * IDIM * DDIM + (size_t)(n0 + brow) * DDIM + bcb * 8;
  const float* gsrc = wg + wboff;
  const float* usrc = wu + wboff;

  const int wr = wid >> 1, wc = wid & 1;
  const int fr = lane & 15;
  const int kc = lane >> 4;
  const int rsw = fr & 7;

  f32x4 accg[4][2] = {};
  f32x4 accu[4][2] = {};

  float4 Pg[4], Pu[4];
  // prologue: A(0)->bufA[0]; B(0)->regs->bufB[0]; B(1)->regs; publish.
#pragma unroll
  for (int j = 0; j < 4; ++j) gload16(aptr[j], &A[0][wid * 32][0] + j * 512);
#pragma unroll
  for (int q = 0; q < 4; ++q) { Pg[q] = *(const float4*)(gsrc + q * 4); Pu[q] = *(const float4*)(usrc + q * 4); }
#pragma unroll
  for (int qq = 0; qq < 2; ++qq) {
    const int oc = ((bcb + qq) ^ bswz) * 8;
    *(u16x8*)&Bg[0][brow][oc] = cvt8t(Pg[qq * 2], Pg[qq * 2 + 1]);
    *(u16x8*)&Bu[0][brow][oc] = cvt8t(Pu[qq * 2], Pu[qq * 2 + 1]);
  }
#pragma unroll
  for (int q = 0; q < 4; ++q) { Pg[q] = *(const float4*)(gsrc + 64 + q * 4); Pu[q] = *(const float4*)(usrc + 64 + q * 4); }
  PIPE_WAIT_BAR();

#pragma unroll 2
  for (int t = 0; t < 32; ++t) {
    const int cur = t & 1;
    const int kp  = (t + 1 <= 31) ? (t + 1) * 64 : 31 * 64;  // A prefetch (clamped)
    const int kp2 = (t + 2 <= 31) ? (t + 2) * 64 : 31 * 64;  // B reg prefetch (clamped)

    // 1) A(t+1) direct-to-LDS into bufA[cur^1]  (must stay oldest vmem of this iter)
#pragma unroll
    for (int j = 0; j < 4; ++j) gload16(aptr[j] + kp, &A[cur ^ 1][wid * 32][0] + j * 512);
    __builtin_amdgcn_sched_barrier(0);
    // 2) cvt + ds_write B(t+1) -> bufB[cur^1]  (regs loaded last iter; auto vmcnt)
#pragma unroll
    for (int qq = 0; qq < 2; ++qq) {
      const int oc = ((bcb + qq) ^ bswz) * 8;
      *(u16x8*)&Bg[cur ^ 1][brow][oc] = cvt8t(Pg[qq * 2], Pg[qq * 2 + 1]);
      *(u16x8*)&Bu[cur ^ 1][brow][oc] = cvt8t(Pu[qq * 2], Pu[qq * 2 + 1]);
    }
    // 3) B(t+2) -> regs
#pragma unroll
    for (int q = 0; q < 4; ++q) { Pg[q] = *(const float4*)(gsrc + kp2 + q * 4); Pu[q] = *(const float4*)(usrc + kp2 + q * 4); }
    __builtin_amdgcn_sched_barrier(0);

    // 4) MFMA on buf[cur]
    __builtin_amdgcn_s_setprio(1);
#pragma unroll
    for (int kk = 0; kk < 2; ++kk) {
      bf16x8 a[4], bg[2], bu[2];
      const int cs = ((kk * 4 + kc) ^ rsw) * 8;
#pragma unroll
      for (int mf = 0; mf < 4; ++mf)
        a[mf] = *(const bf16x8*)&A[cur][wr * 64 + mf * 16 + fr][cs];
#pragma unroll
      for (int nf = 0; nf < 2; ++nf) {
        bg[nf] = *(const bf16x8*)&Bg[cur][wc * 32 + nf * 16 + fr][cs];
        bu[nf] = *(const bf16x8*)&Bu[cur][wc * 32 + nf * 16 + fr][cs];
      }
#pragma unroll
      for (int mf = 0; mf < 4; ++mf)
#pragma unroll
        for (int nf = 0; nf < 2; ++nf) {
          accg[mf][nf] = __builtin_amdgcn_mfma_f32_16x16x32_bf16(a[mf], bg[nf], accg[mf][nf], 0, 0, 0);
          accu[mf][nf] = __builtin_amdgcn_mfma_f32_16x16x32_bf16(a[mf], bu[nf], accu[mf][nf], 0, 0, 0);
        }
    }
    __builtin_amdgcn_s_setprio(0);

    // 5) publish buf[cur^1]: A(t+1) gloads retired, ds_writes drained, sync
    PIPE_WAIT_BAR();
  }

#pragma unroll
  for (int mf = 0; mf < 4; ++mf)
#pragma unroll
    for (int nf = 0; nf < 2; ++nf)
#pragma unroll
      for (int j = 0; j < 4; ++j) {
        const int r = wr * 64 + mf * 16 + (lane >> 4) * 4 + j;
        const int s = rslot[r];
        if (s >= 0) {
          const float g = accg[mf][nf][j];
          const float u = accu[mf][nf][j];
          const float hv = g / (1.f + __expf(-g)) * u;
          h[(size_t)s * IDIM + n0 + wc * 32 + nf * 16 + fr] = f2bf(hv);
        }
      }
}

// ---------------- down grouped GEMM: 128M x 128N, K-split x2, full dbuf, 1 barrier/iter ----------------
__global__ __launch_bounds__(256) void down_kernel(
    const unsigned short* __restrict__ h,
    const float* __restrict__ wd,
    const int* __restrict__ cnt, const int* __restrict__ slots,
    const float* __restrict__ wts,
    const int* __restrict__ tilemap, const int* __restrict__ ntiles,
    float* __restrict__ out)
{
  // grid 1280 = 40 tiles x 16 n-panels x 2 k-splits; XCD swizzle, tile fastest
  const int flat = (blockIdx.x & 7) * 160 + (blockIdx.x >> 3);
  const int ti = flat % 40;
  if (ti >= ntiles[0]) return;
  const int em = tilemap[ti];
  const int e = em >> 8;
  const int mt = em & 255;
  const int r2 = flat / 40;
  const int n0 = (r2 & 15) * 128;
  const int ks = r2 >> 4;           // k-split half
  const int kbase = ks * (IDIM / 2);
  const int count = cnt[e];
  const int m0 = mt * 128;

  __shared__ unsigned short A[2][128][64];   // dbuf, 32 KB
  __shared__ unsigned short B[2][128][64];   // dbuf, 32 KB
  __shared__ int rslot[128];
  __shared__ float rw[128];

  const int tid = threadIdx.x;
  const int lane = tid & 63;
  const int wid = tid >> 6;

  if (tid < 128) {
    const int idx = m0 + tid;
    const int safe = slots[e * TTOK + m0];
    const int s = (idx < count) ? slots[e * TTOK + idx] : safe;
    rslot[tid] = (idx < count) ? s : (safe | 0x40000000);
    rw[tid] = (idx < count) ? wts[e * TTOK + idx] : 0.f;
  }
  __syncthreads();

  const int aswz = ((lane & 7) ^ ((lane >> 3) & 7)) * 8;
  const unsigned short* aptr[4];
#pragma unroll
  for (int j = 0; j < 4; ++j) {
    const int arow = wid * 32 + j * 8 + (lane >> 3);
    aptr[j] = h + (size_t)(rslot[arow] & 0x3fffffff) * IDIM + kbase + aswz;
  }

  // B staging: 32 fp32 per thread
  const int brow = tid >> 1;
  const int bcb = (tid & 1) * 4;
  const int bswz = brow & 7;
  const float* bsrc = wd + (size_t)e * DDIM * IDIM + (size_t)(n0 + brow) * IDIM + kbase + bcb * 8;

  const int wr = wid >> 1, wc = wid & 1;
  const int fr = lane & 15;
  const int kc = lane >> 4;
  const int rsw = fr & 7;

  f32x4 acc[4][4] = {};

  float4 Pb[8];
  // prologue: A(0)->bufA[0]; B(0)->regs->bufB[0]; B(1)->regs; publish.
#pragma unroll
  for (int j = 0; j < 4; ++j) gload16(aptr[j], &A[0][wid * 32][0] + j * 512);
#pragma unroll
  for (int q = 0; q < 8; ++q) Pb[q] = *(const float4*)(bsrc + q * 4);
#pragma unroll
  for (int qq = 0; qq < 4; ++qq)
    *(u16x8*)&B[0][brow][((bcb + qq) ^ bswz) * 8] = cvt8t(Pb[qq * 2], Pb[qq * 2 + 1]);
#pragma unroll
  for (int q = 0; q < 8; ++q) Pb[q] = *(const float4*)(bsrc + 64 + q * 4);
  PIPE_WAIT_BAR();

#pragma unroll 2
  for (int t = 0; t < 44; ++t) {
    const int cur = t & 1;
    const int kp  = (t + 1 <= 43) ? (t + 1) * 64 : 43 * 64;
    const int kp2 = (t + 2 <= 43) ? (t + 2) * 64 : 43 * 64;

#pragma unroll
    for (int j = 0; j < 4; ++j) gload16(aptr[j] + kp, &A[cur ^ 1][wid * 32][0] + j * 512);
    __builtin_amdgcn_sched_barrier(0);
#pragma unroll
    for (int qq = 0; qq < 4; ++qq)
      *(u16x8*)&B[cur ^ 1][brow][((bcb + qq) ^ bswz) * 8] = cvt8t(Pb[qq * 2], Pb[qq * 2 + 1]);
#pragma unroll
    for (int q = 0; q < 8; ++q) Pb[q] = *(const float4*)(bsrc + kp2 + q * 4);
    __builtin_amdgcn_sched_barrier(0);

    __builtin_amdgcn_s_setprio(1);
#pragma unroll
    for (int kk = 0; kk < 2; ++kk) {
      bf16x8 a[4], b[4];
      const int cs = ((kk * 4 + kc) ^ rsw) * 8;
#pragma unroll
      for (int mf = 0; mf < 4; ++mf)
        a[mf] = *(const bf16x8*)&A[cur][wr * 64 + mf * 16 + fr][cs];
#pragma unroll
      for (int nf = 0; nf < 4; ++nf)
        b[nf] = *(const bf16x8*)&B[cur][wc * 64 + nf * 16 + fr][cs];
#pragma unroll
      for (int mf = 0; mf < 4; ++mf)
#pragma unroll
        for (int nf = 0; nf < 4; ++nf)
          acc[mf][nf] = __builtin_amdgcn_mfma_f32_16x16x32_bf16(a[mf], b[nf], acc[mf][nf], 0, 0, 0);
    }
    __builtin_amdgcn_s_setprio(0);

    PIPE_WAIT_BAR();
  }

#pragma unroll
  for (int mf = 0; mf < 4; ++mf)
#pragma unroll
    for (int j = 0; j < 4; ++j) {
      const int r = wr * 64 + mf * 16 + (lane >> 4) * 4 + j;
      const int s = rslot[r];
      if (!(s & 0x40000000)) {
        const int t2 = s >> 1;
        const float w = rw[r];
#pragma unroll
        for (int nf = 0; nf < 4; ++nf)
          atomicAdd(out + (size_t)t2 * DDIM + n0 + wc * 64 + nf * 16 + fr,
                    acc[mf][nf][j] * w);
      }
    }
}

extern "C" void kernel_launch(void* const* d_in, const int* in_sizes, int n_in,
                              void* d_out, int out_size, void* d_ws, size_t ws_size,
                              hipStream_t stream) {
  const float* x  = (const float*)d_in[0];
  const float* gw = (const float*)d_in[1];
  const float* wg = (const float*)d_in[2];
  const float* wu = (const float*)d_in[3];
  const float* wd = (const float*)d_in[4];
  float* out = (float*)d_out;

  char* ws = (char*)d_ws;
  unsigned short* xbf = (unsigned short*)ws;                       // 8,388,608 B
  unsigned short* h   = (unsigned short*)(ws + 8388608);           // 46,137,344 B
  int*   slots = (int*)(ws + 8388608 + 46137344);                  // 65,536 B
  float* wts   = (float*)(ws + 8388608 + 46137344 + 65536);        // 65,536 B
  int*   cnt   = (int*)(ws + 8388608 + 46137344 + 131072);         // 32 B
  int*   tmap  = (int*)(ws + 8388608 + 46137344 + 131072 + 32);    // 256 B
  int*   ntl   = (int*)(ws + 8388608 + 46137344 + 131072 + 288);   // 4 B

  hipMemsetAsync(cnt, 0, NEXP * sizeof(int), stream);
  hipMemsetAsync(d_out, 0, (size_t)TTOK * DDIM * sizeof(float), stream);

  router_kernel<<<TTOK / 4, 256, 0, stream>>>(x, gw, xbf, cnt, slots, wts);
  plan_kernel<<<1, 64, 0, stream>>>(cnt, tmap, ntl);
  gateup_kernel<<<3520, 256, 0, stream>>>(xbf, wg, wu, cnt, slots, tmap, ntl, h);
  down_kernel<<<1280, 256, 0, stream>>>(h, wd, cnt, slots, wts, tmap, ntl, out);
}

// Round 8
// 816.877 us; speedup vs baseline: 1.4678x; 1.0506x over previous
//
#include <hip/hip_runtime.h>
#include <hip/hip_bf16.h>
#include <stdint.h>

#define TTOK 2048
#define DDIM 2048
#define IDIM 5632
#define NEXP 8

typedef __attribute__((ext_vector_type(8))) short bf16x8;
typedef __attribute__((ext_vector_type(4))) float f32x4;
typedef __attribute__((ext_vector_type(8))) unsigned short u16x8;
typedef __attribute__((ext_vector_type(4))) unsigned short u16x4;

__device__ __forceinline__ unsigned short f2bf(float f) {
  union { float f; uint32_t u; } v; v.f = f;
  uint32_t u = v.u + 0x7fffu + ((v.u >> 16) & 1u);
  return (unsigned short)(u >> 16);
}

__device__ __forceinline__ uint32_t fbits(float f) {
  union { float f; uint32_t u; } v; v.f = f; return v.u;
}

// truncating packed f32x2 -> bf16x2 via v_perm_b32 (1 inst per 2 values)
__device__ __forceinline__ u16x8 cvt8t(float4 a, float4 b) {
  union { u16x8 v; uint32_t w[4]; } r;
  r.w[0] = __builtin_amdgcn_perm(fbits(a.y), fbits(a.x), 0x07060302);
  r.w[1] = __builtin_amdgcn_perm(fbits(a.w), fbits(a.z), 0x07060302);
  r.w[2] = __builtin_amdgcn_perm(fbits(b.y), fbits(b.x), 0x07060302);
  r.w[3] = __builtin_amdgcn_perm(fbits(b.w), fbits(b.z), 0x07060302);
  return r.v;
}

typedef __attribute__((address_space(3))) void lds_t;
typedef const __attribute__((address_space(1))) void gbl_t;
__device__ __forceinline__ void gload16(const void* g, void* l) {
  __builtin_amdgcn_global_load_lds((gbl_t*)g, (lds_t*)l, 16, 0, 0);
}

// single barrier per K-step: retire the 4 A-gloads (oldest of this iter),
// keep the 8 B reg-loads (next-next tile) in flight; drain lgkm.
#define PIPE_WAIT_BAR() asm volatile("s_waitcnt vmcnt(8) lgkmcnt(0)\n\ts_barrier" ::: "memory")

// ---------------- router: logits, top-2, softmax, expert lists, x->bf16 ----------------
__global__ __launch_bounds__(256) void router_kernel(
    const float* __restrict__ x, const float* __restrict__ gw,
    unsigned short* __restrict__ xbf,
    int* __restrict__ cnt, int* __restrict__ slots, float* __restrict__ wts)
{
  const int lane = threadIdx.x & 63;
  const int t = (blockIdx.x * blockDim.x + threadIdx.x) >> 6;  // one wave per token
  const float* xr = x + (size_t)t * DDIM;
  float acc[NEXP];
#pragma unroll
  for (int e = 0; e < NEXP; ++e) acc[e] = 0.f;
#pragma unroll
  for (int it = 0; it < DDIM / 256; ++it) {
    const int d = (it * 64 + lane) * 4;
    const float4 xv = *(const float4*)(xr + d);
    u16x4 xb; xb[0]=f2bf(xv.x); xb[1]=f2bf(xv.y); xb[2]=f2bf(xv.z); xb[3]=f2bf(xv.w);
    *(u16x4*)(xbf + (size_t)t * DDIM + d) = xb;
#pragma unroll
    for (int e = 0; e < NEXP; ++e) {
      const float4 gv = *(const float4*)(gw + (size_t)e * DDIM + d);
      acc[e] += xv.x*gv.x + xv.y*gv.y + xv.z*gv.z + xv.w*gv.w;
    }
  }
#pragma unroll
  for (int e = 0; e < NEXP; ++e) {
    float v = acc[e];
#pragma unroll
    for (int off = 32; off > 0; off >>= 1) v += __shfl_xor(v, off);
    acc[e] = v;
  }
  if (lane == 0) {
    int i0 = 0; float v0 = acc[0];
#pragma unroll
    for (int e = 1; e < NEXP; ++e) if (acc[e] > v0) { v0 = acc[e]; i0 = e; }
    int i1 = -1; float v1 = -3.4e38f;
#pragma unroll
    for (int e = 0; e < NEXP; ++e) { if (e == i0) continue; if (acc[e] > v1) { v1 = acc[e]; i1 = e; } }
    const float e1 = __expf(v1 - v0);
    const float w0 = 1.f / (1.f + e1);
    const float w1 = e1 / (1.f + e1);
    const int p0 = atomicAdd(&cnt[i0], 1);
    slots[i0 * TTOK + p0] = t * 2;     wts[i0 * TTOK + p0] = w0;
    const int p1 = atomicAdd(&cnt[i1], 1);
    slots[i1 * TTOK + p1] = t * 2 + 1; wts[i1 * TTOK + p1] = w1;
  }
}

// ---------------- plan: compact (expert, mt) tile list, BM=256 ----------------
__global__ void plan_kernel(const int* __restrict__ cnt,
                            int* __restrict__ tilemap, int* __restrict__ ntiles)
{
  if (threadIdx.x == 0 && blockIdx.x == 0) {
    int n = 0;
#pragma unroll
    for (int e = 0; e < NEXP; ++e) {
      const int nt = (cnt[e] + 255) >> 8;
      for (int m = 0; m < nt; ++m) tilemap[n++] = (e << 8) | m;
    }
    ntiles[0] = n;   // <= 24
  }
}

// chunk swizzle: 16B chunk c of row r stored at chunk c ^ (r & 7)

// ------ gate+up grouped GEMM: 256M x (128g+128u)N, BK=64, 8 waves, 1 barrier/iter ------
__global__ __launch_bounds__(512, 2) void gateup_kernel(
    const unsigned short* __restrict__ xbf,
    const float* __restrict__ wg, const float* __restrict__ wu,
    const int* __restrict__ cnt, const int* __restrict__ slots,
    const int* __restrict__ tilemap, const int* __restrict__ ntiles,
    unsigned short* __restrict__ h)
{
  // grid 1056 = 24 tile-slots x 44 n-panels; XCD swizzle (q=132), tile fastest
  const int flat = (blockIdx.x & 7) * 132 + (blockIdx.x >> 3);
  const int ti = flat % 24;
  if (ti >= ntiles[0]) return;
  const int em = tilemap[ti];
  const int e = em >> 8;
  const int mt = em & 255;
  const int n0 = (flat / 24) * 128;
  const int count = cnt[e];
  const int m0 = mt * 256;

  __shared__ unsigned short A[2][256][64];    // 64 KB
  __shared__ unsigned short Bg[2][128][64];   // 32 KB
  __shared__ unsigned short Bu[2][128][64];   // 32 KB
  __shared__ int rslot[256];
  __shared__ int rtok[256];

  const int tid = threadIdx.x;
  const int lane = tid & 63;
  const int wid = tid >> 6;

  if (tid < 256) {
    const int idx = m0 + tid;
    const int safe = slots[e * TTOK + m0];
    const int s = (idx < count) ? slots[e * TTOK + idx] : safe;
    rslot[tid] = (idx < count) ? s : -1;
    rtok[tid] = s >> 1;
  }
  __syncthreads();

  // A gather: 4 rounds x (8 waves x 8 rows); source chunk pre-swizzled
  const int aswz = ((lane & 7) ^ ((lane >> 3) & 7)) * 8;
  const unsigned short* aptr[4];
#pragma unroll
  for (int j = 0; j < 4; ++j) {
    const int arow = j * 64 + wid * 8 + (lane >> 3);
    aptr[j] = xbf + (size_t)rtok[arow] * DDIM + aswz;
  }

  // B staging: 16 fp32 per thread per matrix (128 rows, 4 threads/row)
  const int brow = tid >> 2;
  const int bcb = (tid & 3) * 2;      // base 16B-chunk index (of 8)
  const int bswz = brow & 7;
  const size_t wboff = (size_t)e * IDIM * DDIM + (size_t)(n0 + brow) * DDIM + bcb * 8;
  const float* gsrc = wg + wboff;
  const float* usrc = wu + wboff;

  const int wr = wid >> 2;            // 0..1: M half (128 rows)
  const int wc = wid & 3;             // 0..3: 32-col group
  const int fr = lane & 15;
  const int kc = lane >> 4;
  const int rsw = fr & 7;

  f32x4 accg[8][2] = {};
  f32x4 accu[8][2] = {};

  float4 Pg[4], Pu[4];
  // prologue: A(0)->bufA[0]; B(0)->regs->bufB[0]; B(1)->regs; publish.
#pragma unroll
  for (int j = 0; j < 4; ++j) gload16(aptr[j], &A[0][j * 64 + wid * 8][0]);
#pragma unroll
  for (int q = 0; q < 4; ++q) { Pg[q] = *(const float4*)(gsrc + q * 4); Pu[q] = *(const float4*)(usrc + q * 4); }
#pragma unroll
  for (int qq = 0; qq < 2; ++qq) {
    const int oc = ((bcb + qq) ^ bswz) * 8;
    *(u16x8*)&Bg[0][brow][oc] = cvt8t(Pg[qq * 2], Pg[qq * 2 + 1]);
    *(u16x8*)&Bu[0][brow][oc] = cvt8t(Pu[qq * 2], Pu[qq * 2 + 1]);
  }
#pragma unroll
  for (int q = 0; q < 4; ++q) { Pg[q] = *(const float4*)(gsrc + 64 + q * 4); Pu[q] = *(const float4*)(usrc + 64 + q * 4); }
  PIPE_WAIT_BAR();

#pragma unroll 2
  for (int t = 0; t < 32; ++t) {
    const int cur = t & 1;
    const int kp  = (t + 1 <= 31) ? (t + 1) * 64 : 31 * 64;
    const int kp2 = (t + 2 <= 31) ? (t + 2) * 64 : 31 * 64;

    // 1) A(t+1) direct-to-LDS into bufA[cur^1] (stays oldest vmem of this iter)
#pragma unroll
    for (int j = 0; j < 4; ++j) gload16(aptr[j] + kp, &A[cur ^ 1][j * 64 + wid * 8][0]);
    __builtin_amdgcn_sched_barrier(0);
    // 2) cvt + ds_write B(t+1) -> bufB[cur^1]; 3) B(t+2) -> regs
#pragma unroll
    for (int qq = 0; qq < 2; ++qq) {
      const int oc = ((bcb + qq) ^ bswz) * 8;
      *(u16x8*)&Bg[cur ^ 1][brow][oc] = cvt8t(Pg[qq * 2], Pg[qq * 2 + 1]);
      *(u16x8*)&Bu[cur ^ 1][brow][oc] = cvt8t(Pu[qq * 2], Pu[qq * 2 + 1]);
    }
#pragma unroll
    for (int q = 0; q < 4; ++q) { Pg[q] = *(const float4*)(gsrc + kp2 + q * 4); Pu[q] = *(const float4*)(usrc + kp2 + q * 4); }
    __builtin_amdgcn_sched_barrier(0);

    // 4) MFMA on buf[cur], split by kk
#pragma unroll
    for (int kk = 0; kk < 2; ++kk) {
      bf16x8 a[8], bg[2], bu[2];
      const int cs = ((kk * 4 + kc) ^ rsw) * 8;
#pragma unroll
      for (int mf = 0; mf < 8; ++mf)
        a[mf] = *(const bf16x8*)&A[cur][wr * 128 + mf * 16 + fr][cs];
#pragma unroll
      for (int nf = 0; nf < 2; ++nf) {
        bg[nf] = *(const bf16x8*)&Bg[cur][wc * 32 + nf * 16 + fr][cs];
        bu[nf] = *(const bf16x8*)&Bu[cur][wc * 32 + nf * 16 + fr][cs];
      }
      __builtin_amdgcn_s_setprio(1);
#pragma unroll
      for (int mf = 0; mf < 8; ++mf)
#pragma unroll
        for (int nf = 0; nf < 2; ++nf) {
          accg[mf][nf] = __builtin_amdgcn_mfma_f32_16x16x32_bf16(a[mf], bg[nf], accg[mf][nf], 0, 0, 0);
          accu[mf][nf] = __builtin_amdgcn_mfma_f32_16x16x32_bf16(a[mf], bu[nf], accu[mf][nf], 0, 0, 0);
        }
      __builtin_amdgcn_s_setprio(0);
    }

    // 5) publish buf[cur^1]
    PIPE_WAIT_BAR();
  }

#pragma unroll
  for (int mf = 0; mf < 8; ++mf)
#pragma unroll
    for (int nf = 0; nf < 2; ++nf)
#pragma unroll
      for (int j = 0; j < 4; ++j) {
        const int r = wr * 128 + mf * 16 + (lane >> 4) * 4 + j;
        const int s = rslot[r];
        if (s >= 0) {
          const float g = accg[mf][nf][j];
          const float u = accu[mf][nf][j];
          const float hv = g / (1.f + __expf(-g)) * u;
          h[(size_t)s * IDIM + n0 + wc * 32 + nf * 16 + fr] = f2bf(hv);
        }
      }
}

// ------ down grouped GEMM: 256M x 256N, K-split x4, BK=64, 8 waves, 1 barrier/iter ------
__global__ __launch_bounds__(512, 2) void down_kernel(
    const unsigned short* __restrict__ h,
    const float* __restrict__ wd,
    const int* __restrict__ cnt, const int* __restrict__ slots,
    const float* __restrict__ wts,
    const int* __restrict__ tilemap, const int* __restrict__ ntiles,
    float* __restrict__ out)
{
  // grid 768 = 24 tile-slots x 8 n-panels x 4 k-splits; XCD swizzle (q=96), tile fastest
  const int flat = (blockIdx.x & 7) * 96 + (blockIdx.x >> 3);
  const int ti = flat % 24;
  if (ti >= ntiles[0]) return;
  const int em = tilemap[ti];
  const int e = em >> 8;
  const int mt = em & 255;
  const int rest = flat / 24;          // 0..31
  const int n0 = (rest & 7) * 256;
  const int kbase = (rest >> 3) * (IDIM / 4);   // k-split quarter (1408)
  const int count = cnt[e];
  const int m0 = mt * 256;

  __shared__ unsigned short A[2][256][64];   // 64 KB
  __shared__ unsigned short B[2][256][64];   // 64 KB
  __shared__ int rslot[256];
  __shared__ float rw[256];

  const int tid = threadIdx.x;
  const int lane = tid & 63;
  const int wid = tid >> 6;

  if (tid < 256) {
    const int idx = m0 + tid;
    const int safe = slots[e * TTOK + m0];
    const int s = (idx < count) ? slots[e * TTOK + idx] : safe;
    rslot[tid] = (idx < count) ? s : (safe | 0x40000000);
    rw[tid] = (idx < count) ? wts[e * TTOK + idx] : 0.f;
  }
  __syncthreads();

  const int aswz = ((lane & 7) ^ ((lane >> 3) & 7)) * 8;
  const unsigned short* aptr[4];
#pragma unroll
  for (int j = 0; j < 4; ++j) {
    const int arow = j * 64 + wid * 8 + (lane >> 3);
    aptr[j] = h + (size_t)(rslot[arow] & 0x3fffffff) * IDIM + kbase + aswz;
  }

  // B staging: 32 fp32 per thread (256 rows, 2 threads/row)
  const int brow = tid >> 1;
  const int bcb = (tid & 1) * 4;
  const int bswz = brow & 7;
  const float* bsrc = wd + (size_t)e * DDIM * IDIM + (size_t)(n0 + brow) * IDIM + kbase + bcb * 8;

  const int wr = wid >> 2;            // 0..1: M half
  const int wc = wid & 3;             // 0..3: 64-col group
  const int fr = lane & 15;
  const int kc = lane >> 4;
  const int rsw = fr & 7;

  f32x4 acc[8][4] = {};

  float4 Pb[8];
  // prologue
#pragma unroll
  for (int j = 0; j < 4; ++j) gload16(aptr[j], &A[0][j * 64 + wid * 8][0]);
#pragma unroll
  for (int q = 0; q < 8; ++q) Pb[q] = *(const float4*)(bsrc + q * 4);
#pragma unroll
  for (int qq = 0; qq < 4; ++qq)
    *(u16x8*)&B[0][brow][((bcb + qq) ^ bswz) * 8] = cvt8t(Pb[qq * 2], Pb[qq * 2 + 1]);
#pragma unroll
  for (int q = 0; q < 8; ++q) Pb[q] = *(const float4*)(bsrc + 64 + q * 4);
  PIPE_WAIT_BAR();

#pragma unroll 2
  for (int t = 0; t < 22; ++t) {
    const int cur = t & 1;
    const int kp  = (t + 1 <= 21) ? (t + 1) * 64 : 21 * 64;
    const int kp2 = (t + 2 <= 21) ? (t + 2) * 64 : 21 * 64;

#pragma unroll
    for (int j = 0; j < 4; ++j) gload16(aptr[j] + kp, &A[cur ^ 1][j * 64 + wid * 8][0]);
    __builtin_amdgcn_sched_barrier(0);
#pragma unroll
    for (int qq = 0; qq < 4; ++qq)
      *(u16x8*)&B[cur ^ 1][brow][((bcb + qq) ^ bswz) * 8] = cvt8t(Pb[qq * 2], Pb[qq * 2 + 1]);
#pragma unroll
    for (int q = 0; q < 8; ++q) Pb[q] = *(const float4*)(bsrc + kp2 + q * 4);
    __builtin_amdgcn_sched_barrier(0);

#pragma unroll
    for (int kk = 0; kk < 2; ++kk) {
      bf16x8 a[8], b[4];
      const int cs = ((kk * 4 + kc) ^ rsw) * 8;
#pragma unroll
      for (int mf = 0; mf < 8; ++mf)
        a[mf] = *(const bf16x8*)&A[cur][wr * 128 + mf * 16 + fr][cs];
#pragma unroll
      for (int nf = 0; nf < 4; ++nf)
        b[nf] = *(const bf16x8*)&B[cur][wc * 64 + nf * 16 + fr][cs];
      __builtin_amdgcn_s_setprio(1);
#pragma unroll
      for (int mf = 0; mf < 8; ++mf)
#pragma unroll
        for (int nf = 0; nf < 4; ++nf)
          acc[mf][nf] = __builtin_amdgcn_mfma_f32_16x16x32_bf16(a[mf], b[nf], acc[mf][nf], 0, 0, 0);
      __builtin_amdgcn_s_setprio(0);
    }

    PIPE_WAIT_BAR();
  }

#pragma unroll
  for (int mf = 0; mf < 8; ++mf)
#pragma unroll
    for (int j = 0; j < 4; ++j) {
      const int r = wr * 128 + mf * 16 + (lane >> 4) * 4 + j;
      const int s = rslot[r];
      if (!(s & 0x40000000)) {
        const int t2 = s >> 1;
        const float w = rw[r];
#pragma unroll
        for (int nf = 0; nf < 4; ++nf)
          atomicAdd(out + (size_t)t2 * DDIM + n0 + wc * 64 + nf * 16 + fr,
                    acc[mf][nf][j] * w);
      }
    }
}

extern "C" void kernel_launch(void* const* d_in, const int* in_sizes, int n_in,
                              void* d_out, int out_size, void* d_ws, size_t ws_size,
                              hipStream_t stream) {
  const float* x  = (const float*)d_in[0];
  const float* gw = (const float*)d_in[1];
  const float* wg = (const float*)d_in[2];
  const float* wu = (const float*)d_in[3];
  const float* wd = (const float*)d_in[4];
  float* out = (float*)d_out;

  char* ws = (char*)d_ws;
  unsigned short* xbf = (unsigned short*)ws;                       // 8,388,608 B
  unsigned short* h   = (unsigned short*)(ws + 8388608);           // 46,137,344 B
  int*   slots = (int*)(ws + 8388608 + 46137344);                  // 65,536 B
  float* wts   = (float*)(ws + 8388608 + 46137344 + 65536);        // 65,536 B
  int*   cnt   = (int*)(ws + 8388608 + 46137344 + 131072);         // 32 B
  int*   tmap  = (int*)(ws + 8388608 + 46137344 + 131072 + 32);    // 256 B
  int*   ntl   = (int*)(ws + 8388608 + 46137344 + 131072 + 288);   // 4 B

  hipMemsetAsync(cnt, 0, NEXP * sizeof(int), stream);
  hipMemsetAsync(d_out, 0, (size_t)TTOK * DDIM * sizeof(float), stream);

  router_kernel<<<TTOK / 4, 256, 0, stream>>>(x, gw, xbf, cnt, slots, wts);
  plan_kernel<<<1, 64, 0, stream>>>(cnt, tmap, ntl);
  gateup_kernel<<<1056, 512, 0, stream>>>(xbf, wg, wu, cnt, slots, tmap, ntl, h);
  down_kernel<<<768, 512, 0, stream>>>(h, wd, cnt, slots, wts, tmap, ntl, out);
}

// Round 9
// 806.611 us; speedup vs baseline: 1.4865x; 1.0127x over previous
//
#include <hip/hip_runtime.h>
#include <hip/hip_bf16.h>
#include <stdint.h>

#define TTOK 2048
#define DDIM 2048
#define IDIM 5632
#define NEXP 8

typedef __attribute__((ext_vector_type(8))) short bf16x8;
typedef __attribute__((ext_vector_type(4))) float f32x4;
typedef __attribute__((ext_vector_type(8))) unsigned short u16x8;
typedef __attribute__((ext_vector_type(4))) unsigned short u16x4;

__device__ __forceinline__ unsigned short f2bf(float f) {
  union { float f; uint32_t u; } v; v.f = f;
  uint32_t u = v.u + 0x7fffu + ((v.u >> 16) & 1u);
  return (unsigned short)(u >> 16);
}

__device__ __forceinline__ uint32_t fbits(float f) {
  union { float f; uint32_t u; } v; v.f = f; return v.u;
}

// truncating packed f32x2 -> bf16x2 via v_perm_b32 (1 inst per 2 values)
__device__ __forceinline__ u16x8 cvt8t(float4 a, float4 b) {
  union { u16x8 v; uint32_t w[4]; } r;
  r.w[0] = __builtin_amdgcn_perm(fbits(a.y), fbits(a.x), 0x07060302);
  r.w[1] = __builtin_amdgcn_perm(fbits(a.w), fbits(a.z), 0x07060302);
  r.w[2] = __builtin_amdgcn_perm(fbits(b.y), fbits(b.x), 0x07060302);
  r.w[3] = __builtin_amdgcn_perm(fbits(b.w), fbits(b.z), 0x07060302);
  return r.v;
}

typedef __attribute__((address_space(3))) void lds_t;
typedef const __attribute__((address_space(1))) void gbl_t;
__device__ __forceinline__ void gload16(const void* g, void* l) {
  __builtin_amdgcn_global_load_lds((gbl_t*)g, (lds_t*)l, 16, 0, 0);
}

// single barrier per K-step: retire this iter's A-gloads (oldest), keep the
// 4 B reg-loads (next-next tile) in flight; drain lgkm for ds_write publish.
#define PIPE_BAR() asm volatile("s_waitcnt vmcnt(4) lgkmcnt(0)\n\ts_barrier" ::: "memory")

// ---------------- router: logits, top-2, softmax, expert lists, x->bf16 ----------------
__global__ __launch_bounds__(256) void router_kernel(
    const float* __restrict__ x, const float* __restrict__ gw,
    unsigned short* __restrict__ xbf,
    int* __restrict__ cnt, int* __restrict__ slots, float* __restrict__ wts)
{
  const int lane = threadIdx.x & 63;
  const int t = (blockIdx.x * blockDim.x + threadIdx.x) >> 6;  // one wave per token
  const float* xr = x + (size_t)t * DDIM;
  float acc[NEXP];
#pragma unroll
  for (int e = 0; e < NEXP; ++e) acc[e] = 0.f;
#pragma unroll
  for (int it = 0; it < DDIM / 256; ++it) {
    const int d = (it * 64 + lane) * 4;
    const float4 xv = *(const float4*)(xr + d);
    u16x4 xb; xb[0]=f2bf(xv.x); xb[1]=f2bf(xv.y); xb[2]=f2bf(xv.z); xb[3]=f2bf(xv.w);
    *(u16x4*)(xbf + (size_t)t * DDIM + d) = xb;
#pragma unroll
    for (int e = 0; e < NEXP; ++e) {
      const float4 gv = *(const float4*)(gw + (size_t)e * DDIM + d);
      acc[e] += xv.x*gv.x + xv.y*gv.y + xv.z*gv.z + xv.w*gv.w;
    }
  }
#pragma unroll
  for (int e = 0; e < NEXP; ++e) {
    float v = acc[e];
#pragma unroll
    for (int off = 32; off > 0; off >>= 1) v += __shfl_xor(v, off);
    acc[e] = v;
  }
  if (lane == 0) {
    int i0 = 0; float v0 = acc[0];
#pragma unroll
    for (int e = 1; e < NEXP; ++e) if (acc[e] > v0) { v0 = acc[e]; i0 = e; }
    int i1 = -1; float v1 = -3.4e38f;
#pragma unroll
    for (int e = 0; e < NEXP; ++e) { if (e == i0) continue; if (acc[e] > v1) { v1 = acc[e]; i1 = e; } }
    const float e1 = __expf(v1 - v0);
    const float w0 = 1.f / (1.f + e1);
    const float w1 = e1 / (1.f + e1);
    const int p0 = atomicAdd(&cnt[i0], 1);
    slots[i0 * TTOK + p0] = t * 2;     wts[i0 * TTOK + p0] = w0;
    const int p1 = atomicAdd(&cnt[i1], 1);
    slots[i1 * TTOK + p1] = t * 2 + 1; wts[i1 * TTOK + p1] = w1;
  }
}

// ---------------- plan: compact (expert, mt) tile list, BM=128 ----------------
__global__ void plan_kernel(const int* __restrict__ cnt,
                            int* __restrict__ tilemap, int* __restrict__ ntiles)
{
  if (threadIdx.x == 0 && blockIdx.x == 0) {
    int n = 0;
#pragma unroll
    for (int e = 0; e < NEXP; ++e) {
      const int nt = (cnt[e] + 127) >> 7;
      for (int m = 0; m < nt; ++m) tilemap[n++] = (e << 8) | m;
    }
    ntiles[0] = n;   // <= 39
  }
}

// chunk swizzle: 16B chunk c of row r stored at chunk c ^ (r & 7)

// ---- gate+up grouped GEMM: 128M x 64N, g/u split across waves, 16 waves/CU ----
__global__ __launch_bounds__(512, 4) void gateup_kernel(
    const unsigned short* __restrict__ xbf,
    const float* __restrict__ wg, const float* __restrict__ wu,
    const int* __restrict__ cnt, const int* __restrict__ slots,
    const int* __restrict__ tilemap, const int* __restrict__ ntiles,
    unsigned short* __restrict__ h)
{
  // grid 3520 = 40 tile-slots x 88 n-panels; XCD swizzle (q=440), tile fastest
  const int flat = (blockIdx.x & 7) * 440 + (blockIdx.x >> 3);
  const int ti = flat % 40;
  if (ti >= ntiles[0]) return;
  const int em = tilemap[ti];
  const int e = em >> 8;
  const int mt = em & 255;
  const int n0 = (flat / 40) * 64;
  const int count = cnt[e];
  const int m0 = mt * 128;

  __shared__ unsigned short A[2][128][64];    // 32 KB (also reused as u-exchange fp32[128][64])
  __shared__ unsigned short Bg[2][64][64];    // 16 KB
  __shared__ unsigned short Bu[2][64][64];    // 16 KB
  __shared__ int rslot[128];
  __shared__ int rtok[128];

  const int tid = threadIdx.x;
  const int lane = tid & 63;
  const int wid = tid >> 6;

  if (tid < 128) {
    const int idx = m0 + tid;
    const int safe = slots[e * TTOK + m0];
    const int s = (idx < count) ? slots[e * TTOK + idx] : safe;
    rslot[tid] = (idx < count) ? s : -1;
    rtok[tid] = s >> 1;
  }
  __syncthreads();

  // A gather: per-lane global src, chunk pre-swizzled; 2 gloads/thread (512 thr, 16 KB tile)
  const int aswz = ((lane & 7) ^ ((lane >> 3) & 7)) * 8;
  const unsigned short* aptr[2];
#pragma unroll
  for (int j = 0; j < 2; ++j) {
    const int arow = wid * 16 + j * 8 + (lane >> 3);
    aptr[j] = xbf + (size_t)rtok[arow] * DDIM + aswz;
  }

  // wave role: waves 0-3 = gate, 4-7 = up. Each wave stages and consumes its own matrix.
  const int mat = wid >> 2;
  unsigned short (*Bm)[64][64] = (mat == 0) ? Bg : Bu;
  const float* wsel = (mat == 0) ? wg : wu;

  // B staging: 256 threads per matrix, 16 fp32/thread (64 rows x 64 k fp32)
  const int tidm = tid & 255;
  const int brow = tidm >> 2;
  const int bcb = (tidm & 3) * 2;
  const int bswz = brow & 7;
  const float* msrc = wsel + (size_t)e * IDIM * DDIM + (size_t)(n0 + brow) * DDIM + bcb * 8;

  const int wr = (wid >> 1) & 1, wc = wid & 1;
  const int fr = lane & 15;
  const int kc = lane >> 4;
  const int rsw = fr & 7;

  f32x4 acc[4][2] = {};

  float4 P[4];
  // prologue: A(0)->bufA[0] [2 vmem]; B(0)->regs->bufB[0]; B(1)->regs [4 vmem]
#pragma unroll
  for (int j = 0; j < 2; ++j) gload16(aptr[j], &A[0][wid * 16][0] + j * 512);
#pragma unroll
  for (int q = 0; q < 4; ++q) P[q] = *(const float4*)(msrc + q * 4);
#pragma unroll
  for (int qq = 0; qq < 2; ++qq)
    *(u16x8*)&Bm[0][brow][((bcb + qq) ^ bswz) * 8] = cvt8t(P[qq * 2], P[qq * 2 + 1]);
#pragma unroll
  for (int q = 0; q < 4; ++q) P[q] = *(const float4*)(msrc + 64 + q * 4);
  PIPE_BAR();

#pragma unroll 2
  for (int t = 0; t < 32; ++t) {
    const int cur = t & 1;
    const int kp  = (t + 1 <= 31) ? (t + 1) * 64 : 31 * 64;
    const int kp2 = (t + 2 <= 31) ? (t + 2) * 64 : 31 * 64;

    // 1) A(t+1) direct-to-LDS (stays oldest vmem of this iter)
#pragma unroll
    for (int j = 0; j < 2; ++j) gload16(aptr[j] + kp, &A[cur ^ 1][wid * 16][0] + j * 512);
    __builtin_amdgcn_sched_barrier(0);
    // 2) cvt + ds_write B(t+1); 3) B(t+2) -> regs
#pragma unroll
    for (int qq = 0; qq < 2; ++qq)
      *(u16x8*)&Bm[cur ^ 1][brow][((bcb + qq) ^ bswz) * 8] = cvt8t(P[qq * 2], P[qq * 2 + 1]);
#pragma unroll
    for (int q = 0; q < 4; ++q) P[q] = *(const float4*)(msrc + kp2 + q * 4);
    __builtin_amdgcn_sched_barrier(0);

    // 4) MFMA on buf[cur] (own matrix only)
    __builtin_amdgcn_s_setprio(1);
#pragma unroll
    for (int kk = 0; kk < 2; ++kk) {
      bf16x8 a[4], b[2];
      const int cs = ((kk * 4 + kc) ^ rsw) * 8;
#pragma unroll
      for (int mf = 0; mf < 4; ++mf)
        a[mf] = *(const bf16x8*)&A[cur][wr * 64 + mf * 16 + fr][cs];
#pragma unroll
      for (int nf = 0; nf < 2; ++nf)
        b[nf] = *(const bf16x8*)&Bm[cur][wc * 32 + nf * 16 + fr][cs];
#pragma unroll
      for (int mf = 0; mf < 4; ++mf)
#pragma unroll
        for (int nf = 0; nf < 2; ++nf)
          acc[mf][nf] = __builtin_amdgcn_mfma_f32_16x16x32_bf16(a[mf], b[nf], acc[mf][nf], 0, 0, 0);
    }
    __builtin_amdgcn_s_setprio(0);

    // 5) publish buf[cur^1]
    PIPE_BAR();
  }

  // epilogue: u-waves export acc via LDS (overlay on dead A buffer), g-waves fuse SiLU
  __syncthreads();
  float* uex = (float*)&A[0][0][0];   // [128][64] fp32 = 32 KB
  if (mat == 1) {
#pragma unroll
    for (int mf = 0; mf < 4; ++mf)
#pragma unroll
      for (int nf = 0; nf < 2; ++nf)
#pragma unroll
        for (int j = 0; j < 4; ++j) {
          const int r = wr * 64 + mf * 16 + (lane >> 4) * 4 + j;
          const int c = wc * 32 + nf * 16 + fr;
          uex[r * 64 + c] = acc[mf][nf][j];
        }
  }
  __syncthreads();
  if (mat == 0) {
#pragma unroll
    for (int mf = 0; mf < 4; ++mf)
#pragma unroll
      for (int nf = 0; nf < 2; ++nf)
#pragma unroll
        for (int j = 0; j < 4; ++j) {
          const int r = wr * 64 + mf * 16 + (lane >> 4) * 4 + j;
          const int c = wc * 32 + nf * 16 + fr;
          const int s = rslot[r];
          if (s >= 0) {
            const float g = acc[mf][nf][j];
            const float u = uex[r * 64 + c];
            const float hv = g / (1.f + __expf(-g)) * u;
            h[(size_t)s * IDIM + n0 + c] = f2bf(hv);
          }
        }
  }
}

// ---- down grouped GEMM: 128M x 64N, K-split x2, 12 waves/CU, scatter-add ----
__global__ __launch_bounds__(256, 4) void down_kernel(
    const unsigned short* __restrict__ h,
    const float* __restrict__ wd,
    const int* __restrict__ cnt, const int* __restrict__ slots,
    const float* __restrict__ wts,
    const int* __restrict__ tilemap, const int* __restrict__ ntiles,
    float* __restrict__ out)
{
  // grid 2560 = 40 tile-slots x 32 n-panels x 2 k-splits; XCD swizzle (q=320)
  const int flat = (blockIdx.x & 7) * 320 + (blockIdx.x >> 3);
  const int ti = flat % 40;
  if (ti >= ntiles[0]) return;
  const int em = tilemap[ti];
  const int e = em >> 8;
  const int mt = em & 255;
  const int rest = flat / 40;          // 0..63
  const int n0 = (rest & 31) * 64;
  const int kbase = (rest >> 5) * (IDIM / 2);
  const int count = cnt[e];
  const int m0 = mt * 128;

  __shared__ unsigned short A[2][128][64];   // 32 KB
  __shared__ unsigned short B[2][64][64];    // 16 KB
  __shared__ int rslot[128];
  __shared__ float rw[128];

  const int tid = threadIdx.x;
  const int lane = tid & 63;
  const int wid = tid >> 6;

  if (tid < 128) {
    const int idx = m0 + tid;
    const int safe = slots[e * TTOK + m0];
    const int s = (idx < count) ? slots[e * TTOK + idx] : safe;
    rslot[tid] = (idx < count) ? s : (safe | 0x40000000);
    rw[tid] = (idx < count) ? wts[e * TTOK + idx] : 0.f;
  }
  __syncthreads();

  const int aswz = ((lane & 7) ^ ((lane >> 3) & 7)) * 8;
  const unsigned short* aptr[4];
#pragma unroll
  for (int j = 0; j < 4; ++j) {
    const int arow = wid * 32 + j * 8 + (lane >> 3);
    aptr[j] = h + (size_t)(rslot[arow] & 0x3fffffff) * IDIM + kbase + aswz;
  }

  // B staging: 16 fp32 per thread (64 rows x 64 k fp32)
  const int brow = tid >> 2;
  const int bcb = (tid & 3) * 2;
  const int bswz = brow & 7;
  const float* bsrc = wd + (size_t)e * DDIM * IDIM + (size_t)(n0 + brow) * IDIM + kbase + bcb * 8;

  const int wr = wid >> 1, wc = wid & 1;
  const int fr = lane & 15;
  const int kc = lane >> 4;
  const int rsw = fr & 7;

  f32x4 acc[4][2] = {};

  float4 P[4];
  // prologue
#pragma unroll
  for (int j = 0; j < 4; ++j) gload16(aptr[j], &A[0][wid * 32][0] + j * 512);
#pragma unroll
  for (int q = 0; q < 4; ++q) P[q] = *(const float4*)(bsrc + q * 4);
#pragma unroll
  for (int qq = 0; qq < 2; ++qq)
    *(u16x8*)&B[0][brow][((bcb + qq) ^ bswz) * 8] = cvt8t(P[qq * 2], P[qq * 2 + 1]);
#pragma unroll
  for (int q = 0; q < 4; ++q) P[q] = *(const float4*)(bsrc + 64 + q * 4);
  asm volatile("s_waitcnt vmcnt(4) lgkmcnt(0)\n\ts_barrier" ::: "memory");

#pragma unroll 2
  for (int t = 0; t < 44; ++t) {
    const int cur = t & 1;
    const int kp  = (t + 1 <= 43) ? (t + 1) * 64 : 43 * 64;
    const int kp2 = (t + 2 <= 43) ? (t + 2) * 64 : 43 * 64;

#pragma unroll
    for (int j = 0; j < 4; ++j) gload16(aptr[j] + kp, &A[cur ^ 1][wid * 32][0] + j * 512);
    __builtin_amdgcn_sched_barrier(0);
#pragma unroll
    for (int qq = 0; qq < 2; ++qq)
      *(u16x8*)&B[cur ^ 1][brow][((bcb + qq) ^ bswz) * 8] = cvt8t(P[qq * 2], P[qq * 2 + 1]);
#pragma unroll
    for (int q = 0; q < 4; ++q) P[q] = *(const float4*)(bsrc + kp2 + q * 4);
    __builtin_amdgcn_sched_barrier(0);

    __builtin_amdgcn_s_setprio(1);
#pragma unroll
    for (int kk = 0; kk < 2; ++kk) {
      bf16x8 a[4], b[2];
      const int cs = ((kk * 4 + kc) ^ rsw) * 8;
#pragma unroll
      for (int mf = 0; mf < 4; ++mf)
        a[mf] = *(const bf16x8*)&A[cur][wr * 64 + mf * 16 + fr][cs];
#pragma unroll
      for (int nf = 0; nf < 2; ++nf)
        b[nf] = *(const bf16x8*)&B[cur][wc * 32 + nf * 16 + fr][cs];
#pragma unroll
      for (int mf = 0; mf < 4; ++mf)
#pragma unroll
        for (int nf = 0; nf < 2; ++nf)
          acc[mf][nf] = __builtin_amdgcn_mfma_f32_16x16x32_bf16(a[mf], b[nf], acc[mf][nf], 0, 0, 0);
    }
    __builtin_amdgcn_s_setprio(0);

    asm volatile("s_waitcnt vmcnt(4) lgkmcnt(0)\n\ts_barrier" ::: "memory");
  }

#pragma unroll
  for (int mf = 0; mf < 4; ++mf)
#pragma unroll
    for (int j = 0; j < 4; ++j) {
      const int r = wr * 64 + mf * 16 + (lane >> 4) * 4 + j;
      const int s = rslot[r];
      if (!(s & 0x40000000)) {
        const int t2 = s >> 1;
        const float w = rw[r];
#pragma unroll
        for (int nf = 0; nf < 2; ++nf)
          atomicAdd(out + (size_t)t2 * DDIM + n0 + wc * 32 + nf * 16 + fr,
                    acc[mf][nf][j] * w);
      }
    }
}

extern "C" void kernel_launch(void* const* d_in, const int* in_sizes, int n_in,
                              void* d_out, int out_size, void* d_ws, size_t ws_size,
                              hipStream_t stream) {
  const float* x  = (const float*)d_in[0];
  const float* gw = (const float*)d_in[1];
  const float* wg = (const float*)d_in[2];
  const float* wu = (const float*)d_in[3];
  const float* wd = (const float*)d_in[4];
  float* out = (float*)d_out;

  char* ws = (char*)d_ws;
  unsigned short* xbf = (unsigned short*)ws;                       // 8,388,608 B
  unsigned short* h   = (unsigned short*)(ws + 8388608);           // 46,137,344 B
  int*   slots = (int*)(ws + 8388608 + 46137344);                  // 65,536 B
  float* wts   = (float*)(ws + 8388608 + 46137344 + 65536);        // 65,536 B
  int*   cnt   = (int*)(ws + 8388608 + 46137344 + 131072);         // 32 B
  int*   tmap  = (int*)(ws + 8388608 + 46137344 + 131072 + 32);    // 256 B
  int*   ntl   = (int*)(ws + 8388608 + 46137344 + 131072 + 288);   // 4 B

  hipMemsetAsync(cnt, 0, NEXP * sizeof(int), stream);
  hipMemsetAsync(d_out, 0, (size_t)TTOK * DDIM * sizeof(float), stream);

  router_kernel<<<TTOK / 4, 256, 0, stream>>>(x, gw, xbf, cnt, slots, wts);
  plan_kernel<<<1, 64, 0, stream>>>(cnt, tmap, ntl);
  gateup_kernel<<<3520, 512, 0, stream>>>(xbf, wg, wu, cnt, slots, tmap, ntl, h);
  down_kernel<<<2560, 256, 0, stream>>>(h, wd, cnt, slots, wts, tmap, ntl, out);
}